// Round 1
// 261.243 us; speedup vs baseline: 1.0030x; 1.0030x over previous
//
#include <hip/hip_runtime.h>

// Problem constants
#define BATCH 4096
#define NI 1024
#define HID 2048
#define TSTEPS 20
#define NA 45
#define TW 512    // fused j-tile width
#define SROW 520  // S row stride in bf16 elems (512 + 8 pad)
#define MAXS 16   // max distinct alive states per batch element (proven <= 15)

typedef __bf16 bf16x8 __attribute__((ext_vector_type(8)));
typedef float floatx4 __attribute__((ext_vector_type(4)));

struct StepMeta {
    float ac0, ac1, delta, chosen;
    int chg;    // (oldCol<<8)|newCol applied entering this state, or -1
    int dac, mult, pad;
};

__device__ __forceinline__ unsigned short f2bf(float x) {
    union { float f; unsigned int u; } un; un.f = x;
    unsigned int r = un.u + 0x7FFFu + ((un.u >> 16) & 1u);
    return (unsigned short)(r >> 16);
}

// ---------------------------------------------------------------------------
// Kernel 1: per-batch-element 20-step state machine (exact fp32 replication),
// COMPRESSED: emits only distinct alive states. Dead (post-commit) steps are
// dropped (ce*alive == 0). A trailing fixed-point state (delta saturated at
// 0.5, dac=5 forever) is detected and emitted once with a multiplicity.
// Determinism of the FSM guarantees repeats only occur as a trailing fixed
// point, and the distinct-state count is <= 5 discrete + 3 ramp + 6 cam + 1
// commit = 15 < MAXS.
// hdr[b] = (nd, alive_total).
// ---------------------------------------------------------------------------
__global__ void scan_kernel(const float* __restrict__ camera,
                            const int* __restrict__ fb_in, const int* __restrict__ lr_in,
                            const int* __restrict__ jp_in, const int* __restrict__ ss_in,
                            const int* __restrict__ at_in, StepMeta* __restrict__ meta,
                            int2* __restrict__ hdr) {
    int b = blockIdx.x * 256 + threadIdx.x;
    if (b >= BATCH) return;
    float cam0 = camera[2 * b], cam1 = camera[2 * b + 1];
    int afb = fb_in[b], alr = lr_in[b], ajp = jp_in[b], ass = ss_in[b], aat = at_in[b];
    float ac0 = 0.f, ac1 = 0.f, delta = 0.0625f;  // MIN_DELTA = 0.5/8
    int rfb = 0, rlr = 0, rjp = 0, rss = 0, rat = 0;
    bool chosen = false;
    int cam_steps = 0;
    int chgPending = -1;
    bool camzero = (fabsf(cam0) < 1e-5f) && (fabsf(cam1) < 1e-5f);
    int nd = 0, aliveTot = 0;
    float lac0 = 0.f, lac1 = 0.f, ldelta = 0.f, lchosen = 0.f;
    int ldac = -1000;
    for (int t = 0; t < TSTEPS; t++) {
        StepMeta m;
        m.ac0 = ac0; m.ac1 = ac1; m.delta = delta; m.chosen = chosen ? 1.f : 0.f;
        m.chg = chgPending; chgPending = -1;
        bool commit = (camzero || cam_steps >= 6) &&
                      rfb == afb && rlr == alr && rjp == ajp && rss == ass && rat == aat;
        int dac = 0; bool modified = commit;
        if (!modified && rfb != afb) { dac = (afb == 0 ? rfb - 1 + 6  : afb - 1 + 6 ); chgPending = ((2  + rfb) << 8) | (2  + afb); rfb = afb; modified = true; }
        if (!modified && rlr != alr) { dac = (alr == 0 ? rlr - 1 + 8  : alr - 1 + 8 ); chgPending = ((5  + rlr) << 8) | (5  + alr); rlr = alr; modified = true; }
        if (!modified && rjp != ajp) { dac = (ajp == 0 ? rjp - 1 + 10 : ajp - 1 + 10); chgPending = ((8  + rjp) << 8) | (8  + ajp); rjp = ajp; modified = true; }
        if (!modified && rss != ass) { dac = (ass == 0 ? rss - 1 + 11 : ass - 1 + 11); chgPending = ((10 + rss) << 8) | (10 + ass); rss = ass; modified = true; }
        if (!modified && rat != aat) { dac = (aat == 0 ? rat - 1 + 14 : aat - 1 + 14); chgPending = ((14 + rat) << 8) | (14 + aat); rat = aat; modified = true; }
        // NOTE: reference compares BOTH cam0 and cam1 against ac0 (replicated as-is)
        if (!modified && !chosen &&
            (fabsf(cam0 - ac0) > delta * 2.f || fabsf(cam1 - ac0) > delta * 2.f)) {
            dac = 5; delta = fminf(delta * 2.f, 0.5f); modified = true;
        }
        if (!modified) {
            bool incX = cam0 >= ac0, incY = cam1 >= ac1;
            dac = 1 + (incX ? 1 : 0) + (incY ? 2 : 0);
            ac0 += incX ? delta : -delta;
            ac1 += incY ? delta : -delta;
            delta *= 0.5f;
            chosen = true;
            cam_steps++;
        }
        m.dac = dac; m.mult = 1; m.pad = 0;
        // trailing fixed-point detection: identical state => identical forever
        if (nd > 0 && m.chg < 0 && !commit &&
            m.ac0 == lac0 && m.ac1 == lac1 && m.delta == ldelta &&
            m.chosen == lchosen && dac == ldac) {
            meta[b * MAXS + nd - 1].mult = 1 + (TSTEPS - t);
            aliveTot += (TSTEPS - t);
            break;
        }
        meta[b * MAXS + nd] = m;
        lac0 = m.ac0; lac1 = m.ac1; ldelta = m.delta; lchosen = m.chosen; ldac = dac;
        nd++; aliveTot++;
        if (commit) break;  // all remaining steps dead (alive=0 -> ce masked)
    }
    hdr[b] = make_int2(nd, aliveTot);
}

// ---------------------------------------------------------------------------
// Kernel 2 (merged prep): convert_fc (blocks [0,4096)), transpose_w1
// (blocks [4096,6144)), convert_w2 (blocks [6144,6152)) — one launch.
// ---------------------------------------------------------------------------
__global__ void prep_kernel(const float* __restrict__ fc, unsigned short* __restrict__ Ab,
                            const float* __restrict__ W1, unsigned short* __restrict__ Wt,
                            const float* __restrict__ W2, unsigned short* __restrict__ W2T) {
    __shared__ float tile[32][33];
    int bid = blockIdx.x, tid = threadIdx.x;
    if (bid < 4096) {
        int idx = bid * 256 + tid;  // covers BATCH*NI/4
        float4 v = ((const float4*)fc)[idx];
        ushort4 o;
        o.x = f2bf(v.x); o.y = f2bf(v.y); o.z = f2bf(v.z); o.w = f2bf(v.w);
        ((ushort4*)Ab)[idx] = o;
    } else if (bid < 6144) {
        int b2 = bid - 4096;
        int k0 = (b2 & 31) * 32, n0 = (b2 >> 5) * 32;
        int tx = tid & 31, ty = tid >> 5;  // (32, 8)
        for (int i = 0; i < 4; i++)
            tile[ty + 8 * i][tx] = W1[(size_t)(k0 + ty + 8 * i) * HID + n0 + tx];
        __syncthreads();
        for (int i = 0; i < 4; i++) {
            int n = ty + 8 * i;
            Wt[(size_t)(n0 + n) * NI + k0 + tx] = f2bf(tile[tx][n]);
        }
    } else {
        int k = (bid - 6144) * 256 + tid;  // 0..2047
        for (int n = 0; n < 48; n++)
            W2T[(size_t)n * HID + k] = (n < NA) ? f2bf(W2[(size_t)k * NA + n]) : (unsigned short)0;
    }
}

// ---------------------------------------------------------------------------
// Kernel 4: base[4096][2048] = A @ W1[:1024] (bf16 MFMA, global_load_lds
// staging, unpadded 128x32 LDS tiles) with the t=0-constant epilogue folded
// in: + b1 + initial one-hot rows (2,5,8,10,14) + 0.0625*w_delta.
// ---------------------------------------------------------------------------
__global__ __launch_bounds__(256) void gemm_base(const unsigned short* __restrict__ Ab,
                                                 const unsigned short* __restrict__ Wt,
                                                 const float* __restrict__ W1,
                                                 const float* __restrict__ b1,
                                                 float* __restrict__ C) {
    __shared__ __align__(16) __bf16 At[128 * 32];
    __shared__ __align__(16) __bf16 Bt[128 * 32];
    int bn = blockIdx.x, bm = blockIdx.y;
    int m0 = bm * 128, n0 = bn * 128;
    int tid = threadIdx.x;
    int wave = tid >> 6, lane = tid & 63;
    int wr = wave >> 1, wc = wave & 1;
    int l15 = lane & 15, q = lane >> 4;
    floatx4 acc[4][4];
    for (int a = 0; a < 4; a++) for (int c = 0; c < 4; c++) acc[a][c] = (floatx4){0.f, 0.f, 0.f, 0.f};
    for (int k0 = 0; k0 < NI; k0 += 32) {
        __syncthreads();
#pragma unroll
        for (int i = 0; i < 2; i++) {
            int c = i * 256 + tid;
            int row = c >> 2, quarter = c & 3;
            const unsigned short* gA = &Ab[(size_t)(m0 + row) * NI + k0 + quarter * 8];
            const unsigned short* gB = &Wt[(size_t)(n0 + row) * NI + k0 + quarter * 8];
            __builtin_amdgcn_global_load_lds(
                (const __attribute__((address_space(1))) unsigned int*)gA,
                (__attribute__((address_space(3))) unsigned int*)&At[c * 8], 16, 0, 0);
            __builtin_amdgcn_global_load_lds(
                (const __attribute__((address_space(1))) unsigned int*)gB,
                (__attribute__((address_space(3))) unsigned int*)&Bt[c * 8], 16, 0, 0);
        }
        __syncthreads();
        bf16x8 af[4], bf[4];
        for (int mr = 0; mr < 4; mr++)
            af[mr] = *(const bf16x8*)&At[(wr * 64 + mr * 16 + l15) * 32 + q * 8];
        for (int nc = 0; nc < 4; nc++)
            bf[nc] = *(const bf16x8*)&Bt[(wc * 64 + nc * 16 + l15) * 32 + q * 8];
        for (int mr = 0; mr < 4; mr++)
            for (int nc = 0; nc < 4; nc++)
                acc[mr][nc] = __builtin_amdgcn_mfma_f32_16x16x32_bf16(af[mr], bf[nc], acc[mr][nc], 0, 0, 0);
    }
    for (int nc = 0; nc < 4; nc++) {
        int col = n0 + wc * 64 + nc * 16 + l15;
        const float* We = W1 + (size_t)NI * HID + col;
        float cv = b1[col] + We[2 * HID] + We[5 * HID] + We[8 * HID] + We[10 * HID]
                 + We[14 * HID] + 0.0625f * We[46 * HID];
        for (int mr = 0; mr < 4; mr++)
            for (int r = 0; r < 4; r++) {
                int row = m0 + wr * 64 + mr * 16 + q * 4 + r;
                C[(size_t)row * HID + col] = acc[mr][nc][r] + cv;
            }
    }
}

// ---------------------------------------------------------------------------
// Kernel 5: fused per-b MLP + CE over COMPRESSED states (nd <= 15).
// Phase A: h[s] = base + u[s]·w + sw[s] for distinct states only; silu ->
// bf16 S (16 x 512 tile) in LDS. Phase B: MFMA S @ W2T (single 16-row
// M-tile), cross-wave reduce aliased into dead S, parallel CE weighted by
// state multiplicity. LDS ~19 KB -> 8 blocks/CU (100% wave occupancy).
// ---------------------------------------------------------------------------
__global__ __launch_bounds__(256) void fused_mlp(const float* __restrict__ base,
                                                 const float* __restrict__ W1,
                                                 const unsigned short* __restrict__ W2T,
                                                 const float* __restrict__ b2,
                                                 const StepMeta* __restrict__ meta,
                                                 const int2* __restrict__ hdr,
                                                 float* __restrict__ loss_out) {
    __shared__ __align__(16) __bf16 S[MAXS * SROW];      // 16,640 B; rows nd..15 zero
    __shared__ __align__(16) float4 u4s[MAXS];           // (ac0, ac1, delta-d0, chosen)
    __shared__ int chgs[MAXS], dacsS[MAXS], multsS[MAXS];
    __shared__ int swapL[5], nsS, chgMaskS;
    __shared__ float b2s[48];
    __shared__ float ceArr[MAXS];
    __shared__ float pmax[MAXS][12], psum[MAXS][12], mxS[MAXS];

    int b = blockIdx.x, tid = threadIdx.x;
    int wave = tid >> 6, lane = tid & 63, l15 = lane & 15, q = lane >> 4;

    int2 hd = hdr[b];
    int nd = __builtin_amdgcn_readfirstlane(hd.x);

    if (tid < nd) {
        StepMeta m = meta[b * MAXS + tid];
        u4s[tid] = make_float4(m.ac0, m.ac1, m.delta - 0.0625f, m.chosen);
        chgs[tid] = m.chg; dacsS[tid] = m.dac; multsS[tid] = m.mult;
    }
    if (tid >= 64 && tid < 112) {
        int n = tid - 64;
        b2s[n] = (n < NA) ? b2[n] : 0.f;
    }
    // zero the MFMA padding rows nd..15 (row stride 1040 B = 65 uint4)
    {
        uint4 zz = make_uint4(0, 0, 0, 0);
        uint4* z = (uint4*)&S[nd * SROW];
        int n16 = (MAXS - nd) * 65;
        for (int i = tid; i < n16; i += 256) z[i] = zz;
    }
    __syncthreads();
    if (tid == 0) {
        int ns = 0, msk = 0;
        for (int s = 0; s < nd; s++)
            if (chgs[s] >= 0) { swapL[ns++] = chgs[s]; msk |= 1 << s; }
        nsS = ns; chgMaskS = msk;
        for (; ns < 5; ns++) swapL[ns] = 0;
    }
    __syncthreads();

    const float* Wx = W1 + (size_t)NI * HID;
    floatx4 acc[3];
    for (int c = 0; c < 3; c++) acc[c] = (floatx4){0.f, 0.f, 0.f, 0.f};

    int ns = __builtin_amdgcn_readfirstlane(nsS);
    unsigned chgMask = (unsigned)__builtin_amdgcn_readfirstlane(chgMaskS);
    int cA = __builtin_amdgcn_readfirstlane(swapL[0]);
    int cB = __builtin_amdgcn_readfirstlane(swapL[1]);
    int cC = __builtin_amdgcn_readfirstlane(swapL[2]);
    int cD = __builtin_amdgcn_readfirstlane(swapL[3]);
    int cE = __builtin_amdgcn_readfirstlane(swapL[4]);

    for (int jt = 0; jt < 4; jt++) {
        if (jt) __syncthreads();                 // phase-B readers of prev tile done
        int j = jt * TW + 2 * tid;
        // hoisted loads: w-vectors, base, and ALL swap rows (load-only branches)
        float2 w0  = *(const float2*)&Wx[j];
        float2 w1  = *(const float2*)&Wx[HID + j];
        float2 wdl = *(const float2*)&Wx[46 * HID + j];
        float2 wch = *(const float2*)&Wx[47 * HID + j];
        float2 hb  = *(const float2*)&base[(size_t)b * HID + j];  // incl. b1 + t0 consts
        float2 nA = {0,0}, oA = {0,0}, nB = {0,0}, oB = {0,0}, nC = {0,0}, oC = {0,0};
        float2 nD = {0,0}, oD = {0,0}, nE = {0,0}, oE = {0,0};
        if (ns > 0) { nA = *(const float2*)&Wx[(size_t)(cA & 255) * HID + j]; oA = *(const float2*)&Wx[(size_t)(cA >> 8) * HID + j]; }
        if (ns > 1) { nB = *(const float2*)&Wx[(size_t)(cB & 255) * HID + j]; oB = *(const float2*)&Wx[(size_t)(cB >> 8) * HID + j]; }
        if (ns > 2) { nC = *(const float2*)&Wx[(size_t)(cC & 255) * HID + j]; oC = *(const float2*)&Wx[(size_t)(cC >> 8) * HID + j]; }
        if (ns > 3) { nD = *(const float2*)&Wx[(size_t)(cD & 255) * HID + j]; oD = *(const float2*)&Wx[(size_t)(cD >> 8) * HID + j]; }
        if (ns > 4) { nE = *(const float2*)&Wx[(size_t)(cE & 255) * HID + j]; oE = *(const float2*)&Wx[(size_t)(cE >> 8) * HID + j]; }
        float dAx = nA.x - oA.x, dAy = nA.y - oA.y;
        float dBx = nB.x - oB.x, dBy = nB.y - oB.y;
        float dCx = nC.x - oC.x, dCy = nC.y - oC.y;
        float dDx = nD.x - oD.x, dDy = nD.y - oD.y;
        float dEx = nE.x - oE.x, dEy = nE.y - oE.y;
        float sw0 = 0.f, sw1 = 0.f;
        int sc = 0;
        for (int s = 0; s < nd; s++) {
            if ((chgMask >> s) & 1u) {           // uniform (scalar) branch
                float dx = (sc == 0) ? dAx : (sc == 1) ? dBx : (sc == 2) ? dCx : (sc == 3) ? dDx : dEx;
                float dy = (sc == 0) ? dAy : (sc == 1) ? dBy : (sc == 2) ? dCy : (sc == 3) ? dDy : dEy;
                sw0 += dx; sw1 += dy; sc++;
            }
            float4 u = u4s[s];
            float h0 = hb.x + sw0 + u.x * w0.x + u.y * w1.x + u.z * wdl.x + u.w * wch.x;
            float h1 = hb.y + sw1 + u.x * w0.y + u.y * w1.y + u.z * wdl.y + u.w * wch.y;
            float s0 = h0 * __builtin_amdgcn_rcpf(1.f + __expf(-h0));
            float s1 = h1 * __builtin_amdgcn_rcpf(1.f + __expf(-h1));
            union { unsigned int u32; __bf16 h[2]; } pk;
            pk.h[0] = (__bf16)s0; pk.h[1] = (__bf16)s1;   // v_cvt_pk_bf16_f32 (RNE)
            *(unsigned int*)&S[s * SROW + 2 * tid] = pk.u32;
        }
        __syncthreads();
        // Phase B: wave handles K range [wave*128, wave*128+128) of this j-tile
        const __bf16* Wb = (const __bf16*)W2T;
#pragma unroll
        for (int ks = 0; ks < 4; ks++) {
            int kc = wave * 128 + ks * 32 + q * 8;
            bf16x8 a0 = *(const bf16x8*)&S[l15 * SROW + kc];
            int kg = jt * TW + kc;
            bf16x8 b0  = *(const bf16x8*)&Wb[(size_t)l15 * HID + kg];
            bf16x8 b1v = *(const bf16x8*)&Wb[(size_t)(16 + l15) * HID + kg];
            bf16x8 b2v = *(const bf16x8*)&Wb[(size_t)(32 + l15) * HID + kg];
            acc[0] = __builtin_amdgcn_mfma_f32_16x16x32_bf16(a0, b0,  acc[0], 0, 0, 0);
            acc[1] = __builtin_amdgcn_mfma_f32_16x16x32_bf16(a0, b1v, acc[1], 0, 0, 0);
            acc[2] = __builtin_amdgcn_mfma_f32_16x16x32_bf16(a0, b2v, acc[2], 0, 0, 0);
        }
    }
    __syncthreads();
    // cross-wave partials into dead S (C/D layout: col=l15, row=q*4+r)
    float* logitsP = (float*)S;                  // 4*768 floats = 12,288 B
    float* logitsF = (float*)S + 3072;           // 768 floats -> ends at 15,360 B
#pragma unroll
    for (int nt = 0; nt < 3; nt++)
#pragma unroll
        for (int r = 0; r < 4; r++) {
            int t = q * 4 + r;                   // 0..15
            logitsP[(wave * MAXS + t) * 48 + nt * 16 + l15] = acc[nt][r];
        }
    __syncthreads();
    int tE = tid / 12, gE = tid - tE * 12;
    if (tid < 192) {
        float4 p0 = ((const float4*)logitsP)[tid];
        float4 p1 = ((const float4*)logitsP)[192 + tid];
        float4 p2 = ((const float4*)logitsP)[384 + tid];
        float4 p3 = ((const float4*)logitsP)[576 + tid];
        float4 bb = *(const float4*)&b2s[gE * 4];
        float4 r;
        r.x = p0.x + p1.x + p2.x + p3.x + bb.x;
        r.y = p0.y + p1.y + p2.y + p3.y + bb.y;
        r.z = p0.z + p1.z + p2.z + p3.z + bb.z;
        r.w = p0.w + p1.w + p2.w + p3.w + bb.w;
        ((float4*)logitsF)[tid] = r;
        float lm = (gE == 11) ? r.x : fmaxf(fmaxf(r.x, r.y), fmaxf(r.z, r.w));
        pmax[tE][gE] = lm;
    }
    __syncthreads();
    if (tid < 192 && gE == 0) {
        float m = pmax[tE][0];
        for (int i = 1; i < 12; i++) m = fmaxf(m, pmax[tE][i]);
        mxS[tE] = m;
    }
    __syncthreads();
    if (tid < 192) {
        float m = mxS[tE];
        float4 v = ((const float4*)logitsF)[tid];
        float s;
        if (gE == 11) s = __expf(v.x - m);
        else s = __expf(v.x - m) + __expf(v.y - m) + __expf(v.z - m) + __expf(v.w - m);
        psum[tE][gE] = s;
    }
    __syncthreads();
    if (tid < nd) {
        float ssum = 0.f;
        for (int i = 0; i < 12; i++) ssum += psum[tid][i];
        float m = mxS[tid];
        int dac = dacsS[tid];
        float ld = logitsF[tid * 48 + dac];
        float ce = -(ld - m - logf(ssum));
        ceArr[tid] = ce * (float)multsS[tid];
    }
    __syncthreads();
    if (tid == 0) {
        float s = 0.f;
        for (int t = 0; t < nd; t++) s += ceArr[t];
        loss_out[b] = s / (float)hd.y;
    }
}

// ---------------------------------------------------------------------------
// Kernel 6: deterministic final reduction over 4096 per-b losses
// ---------------------------------------------------------------------------
__global__ void reduce_loss(const float* __restrict__ loss, float* __restrict__ out) {
    int tid = threadIdx.x;  // 256
    float s = 0.f;
    for (int i = tid; i < BATCH; i += 256) s += loss[i];
    for (int off = 32; off > 0; off >>= 1) s += __shfl_down(s, off, 64);
    __shared__ float wsum[4];
    if ((tid & 63) == 0) wsum[tid >> 6] = s;
    __syncthreads();
    if (tid == 0) out[0] = (wsum[0] + wsum[1] + wsum[2] + wsum[3]) * (1.0f / (float)BATCH);
}

// ---------------------------------------------------------------------------
extern "C" void kernel_launch(void* const* d_in, const int* in_sizes, int n_in,
                              void* d_out, int out_size, void* d_ws, size_t ws_size,
                              hipStream_t stream) {
    const float* fc_input = (const float*)d_in[0];
    const float* camera   = (const float*)d_in[1];
    const int*   fb       = (const int*)d_in[2];
    const int*   lr       = (const int*)d_in[3];
    const int*   jp       = (const int*)d_in[4];
    const int*   ss       = (const int*)d_in[5];
    const int*   at       = (const int*)d_in[6];
    const float* W1       = (const float*)d_in[7];
    const float* b1       = (const float*)d_in[8];
    const float* W2       = (const float*)d_in[9];
    const float* b2       = (const float*)d_in[10];
    float* out = (float*)d_out;

    char* ws = (char*)d_ws;
    unsigned short* Ab   = (unsigned short*)(ws);                       //  8,388,608 B
    unsigned short* Wt   = (unsigned short*)(ws + 8388608);             //  4,194,304 B
    float*          baseB= (float*)(ws + 12582912);                     // 33,554,432 B
    StepMeta*       meta = (StepMeta*)(ws + 46137344);                  //  2,097,152 B
    int2*           hdr  = (int2*)(ws + 48234496);                      //     32,768 B
    float*          lossB= (float*)(ws + 48267264);                     //     16,384 B
    unsigned short* W2T  = (unsigned short*)(ws + 48283648);            //    196,608 B

    scan_kernel<<<BATCH / 256, 256, 0, stream>>>(camera, fb, lr, jp, ss, at, meta, hdr);
    prep_kernel<<<4096 + 2048 + 8, 256, 0, stream>>>(fc_input, Ab, W1, Wt, W2, W2T);
    gemm_base<<<dim3(HID / 128, BATCH / 128), 256, 0, stream>>>(Ab, Wt, W1, b1, baseB);
    fused_mlp<<<BATCH, 256, 0, stream>>>(baseB, W1, W2T, b2, meta, hdr, lossB);
    reduce_loss<<<1, 256, 0, stream>>>(lossB, out);
}

// Round 2
// 247.429 us; speedup vs baseline: 1.0590x; 1.0558x over previous
//
#include <hip/hip_runtime.h>

// Problem constants
#define BATCH 4096
#define NI 1024
#define HID 2048
#define TSTEPS 20
#define NA 45
#define TW 512    // fused j-tile width
#define SROW 520  // S row stride in bf16 elems (512 + 8 pad)
#define MAXS 16   // max distinct alive states per batch element (proven <= 15)
#define NB 2      // batch elements per fused_mlp block

typedef __bf16 bf16x8 __attribute__((ext_vector_type(8)));
typedef float floatx4 __attribute__((ext_vector_type(4)));

struct StepMeta {
    float ac0, ac1, delta, chosen;
    int chg;    // (oldCol<<8)|newCol applied entering this state, or -1
    int dac, mult, pad;
};

__device__ __forceinline__ unsigned short f2bf(float x) {
    union { float f; unsigned int u; } un; un.f = x;
    unsigned int r = un.u + 0x7FFFu + ((un.u >> 16) & 1u);
    return (unsigned short)(r >> 16);
}

// ---------------------------------------------------------------------------
// Per-batch-element 20-step state machine (exact fp32 replication),
// COMPRESSED: emits only distinct alive states; trailing fixed point gets a
// multiplicity; post-commit steps dropped. nd <= 15 < MAXS.
// ---------------------------------------------------------------------------
__device__ void scan_one(int b, const float* __restrict__ camera,
                         const int* __restrict__ fb_in, const int* __restrict__ lr_in,
                         const int* __restrict__ jp_in, const int* __restrict__ ss_in,
                         const int* __restrict__ at_in, StepMeta* __restrict__ meta,
                         int2* __restrict__ hdr) {
    float cam0 = camera[2 * b], cam1 = camera[2 * b + 1];
    int afb = fb_in[b], alr = lr_in[b], ajp = jp_in[b], ass = ss_in[b], aat = at_in[b];
    float ac0 = 0.f, ac1 = 0.f, delta = 0.0625f;  // MIN_DELTA = 0.5/8
    int rfb = 0, rlr = 0, rjp = 0, rss = 0, rat = 0;
    bool chosen = false;
    int cam_steps = 0;
    int chgPending = -1;
    bool camzero = (fabsf(cam0) < 1e-5f) && (fabsf(cam1) < 1e-5f);
    int nd = 0, aliveTot = 0;
    float lac0 = 0.f, lac1 = 0.f, ldelta = 0.f, lchosen = 0.f;
    int ldac = -1000;
    for (int t = 0; t < TSTEPS; t++) {
        StepMeta m;
        m.ac0 = ac0; m.ac1 = ac1; m.delta = delta; m.chosen = chosen ? 1.f : 0.f;
        m.chg = chgPending; chgPending = -1;
        bool commit = (camzero || cam_steps >= 6) &&
                      rfb == afb && rlr == alr && rjp == ajp && rss == ass && rat == aat;
        int dac = 0; bool modified = commit;
        if (!modified && rfb != afb) { dac = (afb == 0 ? rfb - 1 + 6  : afb - 1 + 6 ); chgPending = ((2  + rfb) << 8) | (2  + afb); rfb = afb; modified = true; }
        if (!modified && rlr != alr) { dac = (alr == 0 ? rlr - 1 + 8  : alr - 1 + 8 ); chgPending = ((5  + rlr) << 8) | (5  + alr); rlr = alr; modified = true; }
        if (!modified && rjp != ajp) { dac = (ajp == 0 ? rjp - 1 + 10 : ajp - 1 + 10); chgPending = ((8  + rjp) << 8) | (8  + ajp); rjp = ajp; modified = true; }
        if (!modified && rss != ass) { dac = (ass == 0 ? rss - 1 + 11 : ass - 1 + 11); chgPending = ((10 + rss) << 8) | (10 + ass); rss = ass; modified = true; }
        if (!modified && rat != aat) { dac = (aat == 0 ? rat - 1 + 14 : aat - 1 + 14); chgPending = ((14 + rat) << 8) | (14 + aat); rat = aat; modified = true; }
        // NOTE: reference compares BOTH cam0 and cam1 against ac0 (replicated as-is)
        if (!modified && !chosen &&
            (fabsf(cam0 - ac0) > delta * 2.f || fabsf(cam1 - ac0) > delta * 2.f)) {
            dac = 5; delta = fminf(delta * 2.f, 0.5f); modified = true;
        }
        if (!modified) {
            bool incX = cam0 >= ac0, incY = cam1 >= ac1;
            dac = 1 + (incX ? 1 : 0) + (incY ? 2 : 0);
            ac0 += incX ? delta : -delta;
            ac1 += incY ? delta : -delta;
            delta *= 0.5f;
            chosen = true;
            cam_steps++;
        }
        m.dac = dac; m.mult = 1; m.pad = 0;
        // trailing fixed-point detection: identical state => identical forever
        if (nd > 0 && m.chg < 0 && !commit &&
            m.ac0 == lac0 && m.ac1 == lac1 && m.delta == ldelta &&
            m.chosen == lchosen && dac == ldac) {
            meta[b * MAXS + nd - 1].mult = 1 + (TSTEPS - t);
            aliveTot += (TSTEPS - t);
            break;
        }
        meta[b * MAXS + nd] = m;
        lac0 = m.ac0; lac1 = m.ac1; ldelta = m.delta; lchosen = m.chosen; ldac = dac;
        nd++; aliveTot++;
        if (commit) break;  // all remaining steps dead (alive=0 -> ce masked)
    }
    hdr[b] = make_int2(nd, aliveTot);
}

// ---------------------------------------------------------------------------
// Merged prep: convert_fc (blocks [0,4096)), transpose_w1 ([4096,6144)),
// convert_w2 ([6144,6152)), scan FSM ([6152,6168)) — one launch.
// ---------------------------------------------------------------------------
__global__ void prep_kernel(const float* __restrict__ fc, unsigned short* __restrict__ Ab,
                            const float* __restrict__ W1, unsigned short* __restrict__ Wt,
                            const float* __restrict__ W2, unsigned short* __restrict__ W2T,
                            const float* __restrict__ camera,
                            const int* __restrict__ fb_in, const int* __restrict__ lr_in,
                            const int* __restrict__ jp_in, const int* __restrict__ ss_in,
                            const int* __restrict__ at_in, StepMeta* __restrict__ meta,
                            int2* __restrict__ hdr) {
    __shared__ float tile[32][33];
    int bid = blockIdx.x, tid = threadIdx.x;
    if (bid < 4096) {
        int idx = bid * 256 + tid;  // covers BATCH*NI/4
        float4 v = ((const float4*)fc)[idx];
        ushort4 o;
        o.x = f2bf(v.x); o.y = f2bf(v.y); o.z = f2bf(v.z); o.w = f2bf(v.w);
        ((ushort4*)Ab)[idx] = o;
    } else if (bid < 6144) {
        int b2 = bid - 4096;
        int k0 = (b2 & 31) * 32, n0 = (b2 >> 5) * 32;
        int tx = tid & 31, ty = tid >> 5;  // (32, 8)
        for (int i = 0; i < 4; i++)
            tile[ty + 8 * i][tx] = W1[(size_t)(k0 + ty + 8 * i) * HID + n0 + tx];
        __syncthreads();
        for (int i = 0; i < 4; i++) {
            int n = ty + 8 * i;
            Wt[(size_t)(n0 + n) * NI + k0 + tx] = f2bf(tile[tx][n]);
        }
    } else if (bid < 6152) {
        int k = (bid - 6144) * 256 + tid;  // 0..2047
        for (int n = 0; n < 48; n++)
            W2T[(size_t)n * HID + k] = (n < NA) ? f2bf(W2[(size_t)k * NA + n]) : (unsigned short)0;
    } else {
        int b = (bid - 6152) * 256 + tid;  // 0..4095
        scan_one(b, camera, fb_in, lr_in, jp_in, ss_in, at_in, meta, hdr);
    }
}

// ---------------------------------------------------------------------------
// GEMM: base[4096][2048] = A @ W1[:1024] (bf16 MFMA, global_load_lds
// staging) + t=0-constant epilogue (b1 + initial one-hots + 0.0625*w_delta).
// ---------------------------------------------------------------------------
__global__ __launch_bounds__(256) void gemm_base(const unsigned short* __restrict__ Ab,
                                                 const unsigned short* __restrict__ Wt,
                                                 const float* __restrict__ W1,
                                                 const float* __restrict__ b1,
                                                 float* __restrict__ C) {
    __shared__ __align__(16) __bf16 At[128 * 32];
    __shared__ __align__(16) __bf16 Bt[128 * 32];
    int bn = blockIdx.x, bm = blockIdx.y;
    int m0 = bm * 128, n0 = bn * 128;
    int tid = threadIdx.x;
    int wave = tid >> 6, lane = tid & 63;
    int wr = wave >> 1, wc = wave & 1;
    int l15 = lane & 15, q = lane >> 4;
    floatx4 acc[4][4];
    for (int a = 0; a < 4; a++) for (int c = 0; c < 4; c++) acc[a][c] = (floatx4){0.f, 0.f, 0.f, 0.f};
    for (int k0 = 0; k0 < NI; k0 += 32) {
        __syncthreads();
#pragma unroll
        for (int i = 0; i < 2; i++) {
            int c = i * 256 + tid;
            int row = c >> 2, quarter = c & 3;
            const unsigned short* gA = &Ab[(size_t)(m0 + row) * NI + k0 + quarter * 8];
            const unsigned short* gB = &Wt[(size_t)(n0 + row) * NI + k0 + quarter * 8];
            __builtin_amdgcn_global_load_lds(
                (const __attribute__((address_space(1))) unsigned int*)gA,
                (__attribute__((address_space(3))) unsigned int*)&At[c * 8], 16, 0, 0);
            __builtin_amdgcn_global_load_lds(
                (const __attribute__((address_space(1))) unsigned int*)gB,
                (__attribute__((address_space(3))) unsigned int*)&Bt[c * 8], 16, 0, 0);
        }
        __syncthreads();
        bf16x8 af[4], bf[4];
        for (int mr = 0; mr < 4; mr++)
            af[mr] = *(const bf16x8*)&At[(wr * 64 + mr * 16 + l15) * 32 + q * 8];
        for (int nc = 0; nc < 4; nc++)
            bf[nc] = *(const bf16x8*)&Bt[(wc * 64 + nc * 16 + l15) * 32 + q * 8];
        for (int mr = 0; mr < 4; mr++)
            for (int nc = 0; nc < 4; nc++)
                acc[mr][nc] = __builtin_amdgcn_mfma_f32_16x16x32_bf16(af[mr], bf[nc], acc[mr][nc], 0, 0, 0);
    }
    for (int nc = 0; nc < 4; nc++) {
        int col = n0 + wc * 64 + nc * 16 + l15;
        const float* We = W1 + (size_t)NI * HID + col;
        float cv = b1[col] + We[2 * HID] + We[5 * HID] + We[8 * HID] + We[10 * HID]
                 + We[14 * HID] + 0.0625f * We[46 * HID];
        for (int mr = 0; mr < 4; mr++)
            for (int r = 0; r < 4; r++) {
                int row = m0 + wr * 64 + mr * 16 + q * 4 + r;
                C[(size_t)row * HID + col] = acc[mr][nc][r] + cv;
            }
    }
}

// ---------------------------------------------------------------------------
// Fused MLP + CE over COMPRESSED states, NB=2 batch elements per block.
// 512 threads / 8 waves. Phase A: threads [0,256) handle b0, [256,512) b1
// (identical W1-row loads -> L1 broadcast). Phase B: waves 0-3 -> b0 rows
// 0-15, waves 4-7 -> b1 rows 16-31, same W2T addresses across groups ->
// W2T L2 traffic per batch element HALVED. 4 blocks/CU, 32 waves/CU.
// ---------------------------------------------------------------------------
__global__ __launch_bounds__(512, 8) void fused_mlp(const float* __restrict__ base,
                                                 const float* __restrict__ W1,
                                                 const unsigned short* __restrict__ W2T,
                                                 const float* __restrict__ b2,
                                                 const StepMeta* __restrict__ meta,
                                                 const int2* __restrict__ hdr,
                                                 float* __restrict__ loss_out) {
    __shared__ __align__(16) __bf16 S[NB * MAXS * SROW];   // 33,280 B; pad rows zero
    __shared__ __align__(16) float4 u4s[NB][MAXS];         // (ac0, ac1, delta-d0, chosen)
    __shared__ int chgs[NB][MAXS], dacsS[NB][MAXS], multsS[NB][MAXS];
    __shared__ int swapL[NB][5], nsS[NB], chgMaskS[NB], ndS[NB], atS[NB];
    __shared__ float b2s[48];
    __shared__ float ceArr[NB][MAXS];
    __shared__ float pmax[NB][MAXS][12], psum[NB][MAXS][12], mxS[NB][MAXS];

    int bp = blockIdx.x, tid = threadIdx.x;
    int tg = tid >> 8, tl = tid & 255;           // group (=b within pair), local tid
    int wave = tid >> 6, lane = tid & 63, l15 = lane & 15, q = lane >> 4;
    int kw = wave & 3;                           // K-chunk within group (phase B)

    if (tl == 0) {
        int2 hd = hdr[bp * NB + tg];
        ndS[tg] = hd.x; atS[tg] = hd.y;
    }
    if (tl < MAXS) {
        StepMeta m = meta[(size_t)(bp * NB + tg) * MAXS + tl];
        u4s[tg][tl] = make_float4(m.ac0, m.ac1, m.delta - 0.0625f, m.chosen);
        chgs[tg][tl] = m.chg; dacsS[tg][tl] = m.dac; multsS[tg][tl] = m.mult;
    }
    if (tid >= 64 && tid < 112) {
        int n = tid - 64;
        b2s[n] = (n < NA) ? b2[n] : 0.f;
    }
    __syncthreads();
    if (tl == 0) {
        int ns = 0, msk = 0, nd = ndS[tg];
        for (int s = 0; s < nd; s++)
            if (chgs[tg][s] >= 0) { swapL[tg][ns++] = chgs[tg][s]; msk |= 1 << s; }
        nsS[tg] = ns; chgMaskS[tg] = msk;
        for (; ns < 5; ns++) swapL[tg][ns] = 0;
    }
    // zero the MFMA padding rows (row = 1040 B = 65 uint4)
    {
        int nd0 = ndS[0], nd1 = ndS[1];
        uint4 zz = make_uint4(0, 0, 0, 0);
        uint4* z0 = (uint4*)&S[(size_t)nd0 * SROW];
        int n0 = (MAXS - nd0) * 65;
        for (int i = tid; i < n0; i += 512) z0[i] = zz;
        uint4* z1 = (uint4*)&S[(size_t)(MAXS + nd1) * SROW];
        int n1 = (MAXS - nd1) * 65;
        for (int i = tid; i < n1; i += 512) z1[i] = zz;
    }
    __syncthreads();

    const float* Wx = W1 + (size_t)NI * HID;
    floatx4 acc[3];
    for (int c = 0; c < 3; c++) acc[c] = (floatx4){0.f, 0.f, 0.f, 0.f};

    int nd = __builtin_amdgcn_readfirstlane(ndS[tg]);
    int ns = __builtin_amdgcn_readfirstlane(nsS[tg]);
    unsigned chgMask = (unsigned)__builtin_amdgcn_readfirstlane(chgMaskS[tg]);
    int cA = __builtin_amdgcn_readfirstlane(swapL[tg][0]);
    int cB = __builtin_amdgcn_readfirstlane(swapL[tg][1]);
    int cC = __builtin_amdgcn_readfirstlane(swapL[tg][2]);
    int cD = __builtin_amdgcn_readfirstlane(swapL[tg][3]);
    int cE = __builtin_amdgcn_readfirstlane(swapL[tg][4]);

    for (int jt = 0; jt < 4; jt++) {
        if (jt) __syncthreads();                 // phase-B readers of prev tile done
        int j = jt * TW + 2 * tl;
        // hoisted loads: w-vectors, base, and ALL swap rows (load-only branches)
        float2 w0  = *(const float2*)&Wx[j];
        float2 w1  = *(const float2*)&Wx[HID + j];
        float2 wdl = *(const float2*)&Wx[46 * HID + j];
        float2 wch = *(const float2*)&Wx[47 * HID + j];
        float2 hb  = *(const float2*)&base[(size_t)(bp * NB + tg) * HID + j];
        float2 nA = {0,0}, oA = {0,0}, nB = {0,0}, oB = {0,0}, nC = {0,0}, oC = {0,0};
        float2 nD = {0,0}, oD = {0,0}, nE = {0,0}, oE = {0,0};
        if (ns > 0) { nA = *(const float2*)&Wx[(size_t)(cA & 255) * HID + j]; oA = *(const float2*)&Wx[(size_t)(cA >> 8) * HID + j]; }
        if (ns > 1) { nB = *(const float2*)&Wx[(size_t)(cB & 255) * HID + j]; oB = *(const float2*)&Wx[(size_t)(cB >> 8) * HID + j]; }
        if (ns > 2) { nC = *(const float2*)&Wx[(size_t)(cC & 255) * HID + j]; oC = *(const float2*)&Wx[(size_t)(cC >> 8) * HID + j]; }
        if (ns > 3) { nD = *(const float2*)&Wx[(size_t)(cD & 255) * HID + j]; oD = *(const float2*)&Wx[(size_t)(cD >> 8) * HID + j]; }
        if (ns > 4) { nE = *(const float2*)&Wx[(size_t)(cE & 255) * HID + j]; oE = *(const float2*)&Wx[(size_t)(cE >> 8) * HID + j]; }
        float dAx = nA.x - oA.x, dAy = nA.y - oA.y;
        float dBx = nB.x - oB.x, dBy = nB.y - oB.y;
        float dCx = nC.x - oC.x, dCy = nC.y - oC.y;
        float dDx = nD.x - oD.x, dDy = nD.y - oD.y;
        float dEx = nE.x - oE.x, dEy = nE.y - oE.y;
        float sw0 = 0.f, sw1 = 0.f;
        int sc = 0;
        for (int s = 0; s < nd; s++) {
            if ((chgMask >> s) & 1u) {           // uniform (scalar) branch
                float dx = (sc == 0) ? dAx : (sc == 1) ? dBx : (sc == 2) ? dCx : (sc == 3) ? dDx : dEx;
                float dy = (sc == 0) ? dAy : (sc == 1) ? dBy : (sc == 2) ? dCy : (sc == 3) ? dDy : dEy;
                sw0 += dx; sw1 += dy; sc++;
            }
            float4 u = u4s[tg][s];
            float h0 = hb.x + sw0 + u.x * w0.x + u.y * w1.x + u.z * wdl.x + u.w * wch.x;
            float h1 = hb.y + sw1 + u.x * w0.y + u.y * w1.y + u.z * wdl.y + u.w * wch.y;
            float s0 = h0 * __builtin_amdgcn_rcpf(1.f + __expf(-h0));
            float s1 = h1 * __builtin_amdgcn_rcpf(1.f + __expf(-h1));
            union { unsigned int u32; __bf16 h[2]; } pk;
            pk.h[0] = (__bf16)s0; pk.h[1] = (__bf16)s1;   // v_cvt_pk_bf16_f32 (RNE)
            *(unsigned int*)&S[(size_t)(tg * MAXS + s) * SROW + 2 * tl] = pk.u32;
        }
        __syncthreads();
        // Phase B: wave group tg (waves 0-3 / 4-7), K chunk kw*128..+128
        const __bf16* Wb = (const __bf16*)W2T;
#pragma unroll
        for (int ks = 0; ks < 4; ks++) {
            int kc = kw * 128 + ks * 32 + q * 8;
            bf16x8 a0 = *(const bf16x8*)&S[(size_t)(tg * MAXS + l15) * SROW + kc];
            int kg = jt * TW + kc;
            bf16x8 b0  = *(const bf16x8*)&Wb[(size_t)l15 * HID + kg];
            bf16x8 b1v = *(const bf16x8*)&Wb[(size_t)(16 + l15) * HID + kg];
            bf16x8 b2v = *(const bf16x8*)&Wb[(size_t)(32 + l15) * HID + kg];
            acc[0] = __builtin_amdgcn_mfma_f32_16x16x32_bf16(a0, b0,  acc[0], 0, 0, 0);
            acc[1] = __builtin_amdgcn_mfma_f32_16x16x32_bf16(a0, b1v, acc[1], 0, 0, 0);
            acc[2] = __builtin_amdgcn_mfma_f32_16x16x32_bf16(a0, b2v, acc[2], 0, 0, 0);
        }
    }
    __syncthreads();
    // cross-wave partials into dead S (C/D layout: col=l15, row=q*4+r)
    // layout: [tg][kw][16][48] floats = 6144 floats (24,576 B) within S (33,280 B)
    float* logitsP = (float*)S;
    float* logitsF = (float*)S + NB * 4 * MAXS * 48;       // +6144 floats, ends 30,720 B
#pragma unroll
    for (int nt = 0; nt < 3; nt++)
#pragma unroll
        for (int r = 0; r < 4; r++) {
            int t = q * 4 + r;                   // 0..15
            logitsP[((size_t)((tg * 4 + kw) * MAXS + t)) * 48 + nt * 16 + l15] = acc[nt][r];
        }
    __syncthreads();
    int tE = tl / 12, gE = tl - tE * 12;
    if (tl < 192) {
        const float4* Pg = (const float4*)(logitsP + tg * 3072);
        float4 p0 = Pg[tl];
        float4 p1 = Pg[192 + tl];
        float4 p2 = Pg[384 + tl];
        float4 p3 = Pg[576 + tl];
        float4 bb = *(const float4*)&b2s[gE * 4];
        float4 r;
        r.x = p0.x + p1.x + p2.x + p3.x + bb.x;
        r.y = p0.y + p1.y + p2.y + p3.y + bb.y;
        r.z = p0.z + p1.z + p2.z + p3.z + bb.z;
        r.w = p0.w + p1.w + p2.w + p3.w + bb.w;
        ((float4*)(logitsF + tg * 768))[tl] = r;
        float lm = (gE == 11) ? r.x : fmaxf(fmaxf(r.x, r.y), fmaxf(r.z, r.w));
        pmax[tg][tE][gE] = lm;
    }
    __syncthreads();
    if (tl < 192 && gE == 0) {
        float m = pmax[tg][tE][0];
        for (int i = 1; i < 12; i++) m = fmaxf(m, pmax[tg][tE][i]);
        mxS[tg][tE] = m;
    }
    __syncthreads();
    if (tl < 192) {
        float m = mxS[tg][tE];
        float4 v = ((const float4*)(logitsF + tg * 768))[tl];
        float s;
        if (gE == 11) s = __expf(v.x - m);
        else s = __expf(v.x - m) + __expf(v.y - m) + __expf(v.z - m) + __expf(v.w - m);
        psum[tg][tE][gE] = s;
    }
    __syncthreads();
    if (tl < nd) {
        float ssum = 0.f;
        for (int i = 0; i < 12; i++) ssum += psum[tg][tl][i];
        float m = mxS[tg][tl];
        int dac = dacsS[tg][tl];
        float ld = logitsF[tg * 768 + tl * 48 + dac];
        float ce = -(ld - m - logf(ssum));
        ceArr[tg][tl] = ce * (float)multsS[tg][tl];
    }
    __syncthreads();
    if (tl == 0) {
        float s = 0.f;
        for (int t = 0; t < nd; t++) s += ceArr[tg][t];
        loss_out[bp * NB + tg] = s / (float)atS[tg];
    }
}

// ---------------------------------------------------------------------------
// Deterministic final reduction over 4096 per-b losses
// ---------------------------------------------------------------------------
__global__ void reduce_loss(const float* __restrict__ loss, float* __restrict__ out) {
    int tid = threadIdx.x;  // 256
    float s = 0.f;
    for (int i = tid; i < BATCH; i += 256) s += loss[i];
    for (int off = 32; off > 0; off >>= 1) s += __shfl_down(s, off, 64);
    __shared__ float wsum[4];
    if ((tid & 63) == 0) wsum[tid >> 6] = s;
    __syncthreads();
    if (tid == 0) out[0] = (wsum[0] + wsum[1] + wsum[2] + wsum[3]) * (1.0f / (float)BATCH);
}

// ---------------------------------------------------------------------------
extern "C" void kernel_launch(void* const* d_in, const int* in_sizes, int n_in,
                              void* d_out, int out_size, void* d_ws, size_t ws_size,
                              hipStream_t stream) {
    const float* fc_input = (const float*)d_in[0];
    const float* camera   = (const float*)d_in[1];
    const int*   fb       = (const int*)d_in[2];
    const int*   lr       = (const int*)d_in[3];
    const int*   jp       = (const int*)d_in[4];
    const int*   ss       = (const int*)d_in[5];
    const int*   at       = (const int*)d_in[6];
    const float* W1       = (const float*)d_in[7];
    const float* b1       = (const float*)d_in[8];
    const float* W2       = (const float*)d_in[9];
    const float* b2       = (const float*)d_in[10];
    float* out = (float*)d_out;

    char* ws = (char*)d_ws;
    unsigned short* Ab   = (unsigned short*)(ws);                       //  8,388,608 B
    unsigned short* Wt   = (unsigned short*)(ws + 8388608);             //  4,194,304 B
    float*          baseB= (float*)(ws + 12582912);                     // 33,554,432 B
    StepMeta*       meta = (StepMeta*)(ws + 46137344);                  //  2,097,152 B
    int2*           hdr  = (int2*)(ws + 48234496);                      //     32,768 B
    float*          lossB= (float*)(ws + 48267264);                     //     16,384 B
    unsigned short* W2T  = (unsigned short*)(ws + 48283648);            //    196,608 B

    prep_kernel<<<4096 + 2048 + 8 + 16, 256, 0, stream>>>(fc_input, Ab, W1, Wt, W2, W2T,
                                                          camera, fb, lr, jp, ss, at, meta, hdr);
    gemm_base<<<dim3(HID / 128, BATCH / 128), 256, 0, stream>>>(Ab, Wt, W1, b1, baseB);
    fused_mlp<<<BATCH / NB, 512, 0, stream>>>(baseB, W1, W2T, b2, meta, hdr, lossB);
    reduce_loss<<<1, 256, 0, stream>>>(lossB, out);
}

// Round 3
// 233.727 us; speedup vs baseline: 1.1211x; 1.0586x over previous
//
#include <hip/hip_runtime.h>

// Problem constants
#define BATCH 4096
#define NI 1024
#define HID 2048
#define TSTEPS 20
#define NA 45
#define TW 512    // fused j-tile width
#define SROW 520  // S row stride in bf16 elems (512 + 8 pad)
#define MAXS 16   // max distinct alive states per batch element (proven <= 15)
#define NB 2      // batch elements per fused_mlp block

typedef __bf16 bf16x8 __attribute__((ext_vector_type(8)));
typedef float floatx4 __attribute__((ext_vector_type(4)));

struct StepMeta {
    float ac0, ac1, delta, chosen;
    int chg;    // (oldCol<<8)|newCol applied entering this state, or -1
    int dac, mult, pad;
};

__device__ __forceinline__ unsigned short f2bf(float x) {
    union { float f; unsigned int u; } un; un.f = x;
    unsigned int r = un.u + 0x7FFFu + ((un.u >> 16) & 1u);
    return (unsigned short)(r >> 16);
}

// ---------------------------------------------------------------------------
// Per-batch-element 20-step state machine (exact fp32 replication),
// COMPRESSED: emits only distinct alive states; trailing fixed point gets a
// multiplicity; post-commit steps dropped. nd <= 15 < MAXS.
// ---------------------------------------------------------------------------
__device__ void scan_one(int b, const float* __restrict__ camera,
                         const int* __restrict__ fb_in, const int* __restrict__ lr_in,
                         const int* __restrict__ jp_in, const int* __restrict__ ss_in,
                         const int* __restrict__ at_in, StepMeta* __restrict__ meta,
                         int2* __restrict__ hdr) {
    float cam0 = camera[2 * b], cam1 = camera[2 * b + 1];
    int afb = fb_in[b], alr = lr_in[b], ajp = jp_in[b], ass = ss_in[b], aat = at_in[b];
    float ac0 = 0.f, ac1 = 0.f, delta = 0.0625f;  // MIN_DELTA = 0.5/8
    int rfb = 0, rlr = 0, rjp = 0, rss = 0, rat = 0;
    bool chosen = false;
    int cam_steps = 0;
    int chgPending = -1;
    bool camzero = (fabsf(cam0) < 1e-5f) && (fabsf(cam1) < 1e-5f);
    int nd = 0, aliveTot = 0;
    float lac0 = 0.f, lac1 = 0.f, ldelta = 0.f, lchosen = 0.f;
    int ldac = -1000;
    for (int t = 0; t < TSTEPS; t++) {
        StepMeta m;
        m.ac0 = ac0; m.ac1 = ac1; m.delta = delta; m.chosen = chosen ? 1.f : 0.f;
        m.chg = chgPending; chgPending = -1;
        bool commit = (camzero || cam_steps >= 6) &&
                      rfb == afb && rlr == alr && rjp == ajp && rss == ass && rat == aat;
        int dac = 0; bool modified = commit;
        if (!modified && rfb != afb) { dac = (afb == 0 ? rfb - 1 + 6  : afb - 1 + 6 ); chgPending = ((2  + rfb) << 8) | (2  + afb); rfb = afb; modified = true; }
        if (!modified && rlr != alr) { dac = (alr == 0 ? rlr - 1 + 8  : alr - 1 + 8 ); chgPending = ((5  + rlr) << 8) | (5  + alr); rlr = alr; modified = true; }
        if (!modified && rjp != ajp) { dac = (ajp == 0 ? rjp - 1 + 10 : ajp - 1 + 10); chgPending = ((8  + rjp) << 8) | (8  + ajp); rjp = ajp; modified = true; }
        if (!modified && rss != ass) { dac = (ass == 0 ? rss - 1 + 11 : ass - 1 + 11); chgPending = ((10 + rss) << 8) | (10 + ass); rss = ass; modified = true; }
        if (!modified && rat != aat) { dac = (aat == 0 ? rat - 1 + 14 : aat - 1 + 14); chgPending = ((14 + rat) << 8) | (14 + aat); rat = aat; modified = true; }
        // NOTE: reference compares BOTH cam0 and cam1 against ac0 (replicated as-is)
        if (!modified && !chosen &&
            (fabsf(cam0 - ac0) > delta * 2.f || fabsf(cam1 - ac0) > delta * 2.f)) {
            dac = 5; delta = fminf(delta * 2.f, 0.5f); modified = true;
        }
        if (!modified) {
            bool incX = cam0 >= ac0, incY = cam1 >= ac1;
            dac = 1 + (incX ? 1 : 0) + (incY ? 2 : 0);
            ac0 += incX ? delta : -delta;
            ac1 += incY ? delta : -delta;
            delta *= 0.5f;
            chosen = true;
            cam_steps++;
        }
        m.dac = dac; m.mult = 1; m.pad = 0;
        // trailing fixed-point detection: identical state => identical forever
        if (nd > 0 && m.chg < 0 && !commit &&
            m.ac0 == lac0 && m.ac1 == lac1 && m.delta == ldelta &&
            m.chosen == lchosen && dac == ldac) {
            meta[b * MAXS + nd - 1].mult = 1 + (TSTEPS - t);
            aliveTot += (TSTEPS - t);
            break;
        }
        meta[b * MAXS + nd] = m;
        lac0 = m.ac0; lac1 = m.ac1; ldelta = m.delta; lchosen = m.chosen; ldac = dac;
        nd++; aliveTot++;
        if (commit) break;  // all remaining steps dead (alive=0 -> ce masked)
    }
    hdr[b] = make_int2(nd, aliveTot);
}

// ---------------------------------------------------------------------------
// Merged prep: convert_fc (blocks [0,4096)), transpose_w1 ([4096,6144)),
// convert_w2 ([6144,6152)), scan FSM ([6152,6168)) — one launch.
// ---------------------------------------------------------------------------
__global__ void prep_kernel(const float* __restrict__ fc, unsigned short* __restrict__ Ab,
                            const float* __restrict__ W1, unsigned short* __restrict__ Wt,
                            const float* __restrict__ W2, unsigned short* __restrict__ W2T,
                            const float* __restrict__ camera,
                            const int* __restrict__ fb_in, const int* __restrict__ lr_in,
                            const int* __restrict__ jp_in, const int* __restrict__ ss_in,
                            const int* __restrict__ at_in, StepMeta* __restrict__ meta,
                            int2* __restrict__ hdr) {
    __shared__ float tile[32][33];
    int bid = blockIdx.x, tid = threadIdx.x;
    if (bid < 4096) {
        int idx = bid * 256 + tid;  // covers BATCH*NI/4
        float4 v = ((const float4*)fc)[idx];
        ushort4 o;
        o.x = f2bf(v.x); o.y = f2bf(v.y); o.z = f2bf(v.z); o.w = f2bf(v.w);
        ((ushort4*)Ab)[idx] = o;
    } else if (bid < 6144) {
        int b2 = bid - 4096;
        int k0 = (b2 & 31) * 32, n0 = (b2 >> 5) * 32;
        int tx = tid & 31, ty = tid >> 5;  // (32, 8)
        for (int i = 0; i < 4; i++)
            tile[ty + 8 * i][tx] = W1[(size_t)(k0 + ty + 8 * i) * HID + n0 + tx];
        __syncthreads();
        for (int i = 0; i < 4; i++) {
            int n = ty + 8 * i;
            Wt[(size_t)(n0 + n) * NI + k0 + tx] = f2bf(tile[tx][n]);
        }
    } else if (bid < 6152) {
        int k = (bid - 6144) * 256 + tid;  // 0..2047
        for (int n = 0; n < 48; n++)
            W2T[(size_t)n * HID + k] = (n < NA) ? f2bf(W2[(size_t)k * NA + n]) : (unsigned short)0;
    } else {
        int b = (bid - 6152) * 256 + tid;  // 0..4095
        scan_one(b, camera, fb_in, lr_in, jp_in, ss_in, at_in, meta, hdr);
    }
}

// ---------------------------------------------------------------------------
// GEMM: base[4096][2048] = A @ W1[:1024] (bf16 MFMA, global_load_lds
// staging) + t=0-constant epilogue (b1 + initial one-hots + 0.0625*w_delta).
// ---------------------------------------------------------------------------
__global__ __launch_bounds__(256) void gemm_base(const unsigned short* __restrict__ Ab,
                                                 const unsigned short* __restrict__ Wt,
                                                 const float* __restrict__ W1,
                                                 const float* __restrict__ b1,
                                                 float* __restrict__ C) {
    __shared__ __align__(16) __bf16 At[128 * 32];
    __shared__ __align__(16) __bf16 Bt[128 * 32];
    int bn = blockIdx.x, bm = blockIdx.y;
    int m0 = bm * 128, n0 = bn * 128;
    int tid = threadIdx.x;
    int wave = tid >> 6, lane = tid & 63;
    int wr = wave >> 1, wc = wave & 1;
    int l15 = lane & 15, q = lane >> 4;
    floatx4 acc[4][4];
    for (int a = 0; a < 4; a++) for (int c = 0; c < 4; c++) acc[a][c] = (floatx4){0.f, 0.f, 0.f, 0.f};
    for (int k0 = 0; k0 < NI; k0 += 32) {
        __syncthreads();
#pragma unroll
        for (int i = 0; i < 2; i++) {
            int c = i * 256 + tid;
            int row = c >> 2, quarter = c & 3;
            const unsigned short* gA = &Ab[(size_t)(m0 + row) * NI + k0 + quarter * 8];
            const unsigned short* gB = &Wt[(size_t)(n0 + row) * NI + k0 + quarter * 8];
            __builtin_amdgcn_global_load_lds(
                (const __attribute__((address_space(1))) unsigned int*)gA,
                (__attribute__((address_space(3))) unsigned int*)&At[c * 8], 16, 0, 0);
            __builtin_amdgcn_global_load_lds(
                (const __attribute__((address_space(1))) unsigned int*)gB,
                (__attribute__((address_space(3))) unsigned int*)&Bt[c * 8], 16, 0, 0);
        }
        __syncthreads();
        bf16x8 af[4], bf[4];
        for (int mr = 0; mr < 4; mr++)
            af[mr] = *(const bf16x8*)&At[(wr * 64 + mr * 16 + l15) * 32 + q * 8];
        for (int nc = 0; nc < 4; nc++)
            bf[nc] = *(const bf16x8*)&Bt[(wc * 64 + nc * 16 + l15) * 32 + q * 8];
        for (int mr = 0; mr < 4; mr++)
            for (int nc = 0; nc < 4; nc++)
                acc[mr][nc] = __builtin_amdgcn_mfma_f32_16x16x32_bf16(af[mr], bf[nc], acc[mr][nc], 0, 0, 0);
    }
    for (int nc = 0; nc < 4; nc++) {
        int col = n0 + wc * 64 + nc * 16 + l15;
        const float* We = W1 + (size_t)NI * HID + col;
        float cv = b1[col] + We[2 * HID] + We[5 * HID] + We[8 * HID] + We[10 * HID]
                 + We[14 * HID] + 0.0625f * We[46 * HID];
        for (int mr = 0; mr < 4; mr++)
            for (int r = 0; r < 4; r++) {
                int row = m0 + wr * 64 + mr * 16 + q * 4 + r;
                C[(size_t)row * HID + col] = acc[mr][nc][r] + cv;
            }
    }
}

// ---------------------------------------------------------------------------
// Fused MLP + CE over COMPRESSED states, NB=2 batch elements per block.
// 512 threads / 8 waves. Phase A: threads [0,256) handle b0, [256,512) b1.
// Phase B: ONE M=32 tile (both elements' S rows share each W2T B-fragment);
// K split across ALL 8 waves (wave w -> k-chunks {w, w+8} of each j-tile).
// W2T load-instructions per element HALVED vs round 2 (the per-CU L1
// line-request rate is the hypothesized limiter). Cross-wave reduction is a
// 2-stage LDS tree (waves 4-7 store, waves 0-3 accumulate, 384-thr final).
// ---------------------------------------------------------------------------
__global__ __launch_bounds__(512, 4) void fused_mlp(const float* __restrict__ base,
                                                 const float* __restrict__ W1,
                                                 const unsigned short* __restrict__ W2T,
                                                 const float* __restrict__ b2,
                                                 const StepMeta* __restrict__ meta,
                                                 const int2* __restrict__ hdr,
                                                 float* __restrict__ loss_out) {
    __shared__ __align__(16) __bf16 S[NB * MAXS * SROW];   // 33,280 B; pad rows zero
    __shared__ __align__(16) float4 u4s[NB][MAXS];         // (ac0, ac1, delta-d0, chosen)
    __shared__ int chgs[NB][MAXS], dacsS[NB][MAXS], multsS[NB][MAXS];
    __shared__ int swapL[NB][5], nsS[NB], chgMaskS[NB], ndS[NB], atS[NB];
    __shared__ float b2s[48];
    __shared__ float ceArr[NB][MAXS];
    __shared__ float pmax[NB][MAXS][12], psum[NB][MAXS][12], mxS[NB][MAXS];

    int bp = blockIdx.x, tid = threadIdx.x;
    int tg = tid >> 8, tl = tid & 255;           // group (=b within pair), local tid
    int wave = tid >> 6, lane = tid & 63, l15 = lane & 15, q = lane >> 4;

    if (tl == 0) {
        int2 hd = hdr[bp * NB + tg];
        ndS[tg] = hd.x; atS[tg] = hd.y;
    }
    if (tl < MAXS) {
        StepMeta m = meta[(size_t)(bp * NB + tg) * MAXS + tl];
        u4s[tg][tl] = make_float4(m.ac0, m.ac1, m.delta - 0.0625f, m.chosen);
        chgs[tg][tl] = m.chg; dacsS[tg][tl] = m.dac; multsS[tg][tl] = m.mult;
    }
    if (tid >= 64 && tid < 112) {
        int n = tid - 64;
        b2s[n] = (n < NA) ? b2[n] : 0.f;
    }
    __syncthreads();
    if (tl == 0) {
        int ns = 0, msk = 0, nd = ndS[tg];
        for (int s = 0; s < nd; s++)
            if (chgs[tg][s] >= 0) { swapL[tg][ns++] = chgs[tg][s]; msk |= 1 << s; }
        nsS[tg] = ns; chgMaskS[tg] = msk;
        for (; ns < 5; ns++) swapL[tg][ns] = 0;
    }
    // zero the MFMA padding rows (row = 1040 B = 65 uint4)
    {
        int nd0 = ndS[0], nd1 = ndS[1];
        uint4 zz = make_uint4(0, 0, 0, 0);
        uint4* z0 = (uint4*)&S[(size_t)nd0 * SROW];
        int n0 = (MAXS - nd0) * 65;
        for (int i = tid; i < n0; i += 512) z0[i] = zz;
        uint4* z1 = (uint4*)&S[(size_t)(MAXS + nd1) * SROW];
        int n1 = (MAXS - nd1) * 65;
        for (int i = tid; i < n1; i += 512) z1[i] = zz;
    }
    __syncthreads();

    const float* Wx = W1 + (size_t)NI * HID;
    floatx4 acc[2][3];                           // [M-tile(=element)][n-tile]
    for (int a = 0; a < 2; a++) for (int c = 0; c < 3; c++) acc[a][c] = (floatx4){0.f, 0.f, 0.f, 0.f};

    int nd = __builtin_amdgcn_readfirstlane(ndS[tg]);
    int ns = __builtin_amdgcn_readfirstlane(nsS[tg]);
    unsigned chgMask = (unsigned)__builtin_amdgcn_readfirstlane(chgMaskS[tg]);
    int cA = __builtin_amdgcn_readfirstlane(swapL[tg][0]);
    int cB = __builtin_amdgcn_readfirstlane(swapL[tg][1]);
    int cC = __builtin_amdgcn_readfirstlane(swapL[tg][2]);
    int cD = __builtin_amdgcn_readfirstlane(swapL[tg][3]);
    int cE = __builtin_amdgcn_readfirstlane(swapL[tg][4]);

    for (int jt = 0; jt < 4; jt++) {
        if (jt) __syncthreads();                 // phase-B readers of prev tile done
        int j = jt * TW + 2 * tl;
        // hoisted loads: w-vectors, base, and ALL swap rows (load-only branches)
        float2 w0  = *(const float2*)&Wx[j];
        float2 w1  = *(const float2*)&Wx[HID + j];
        float2 wdl = *(const float2*)&Wx[46 * HID + j];
        float2 wch = *(const float2*)&Wx[47 * HID + j];
        float2 hb  = *(const float2*)&base[(size_t)(bp * NB + tg) * HID + j];
        float2 nA = {0,0}, oA = {0,0}, nB = {0,0}, oB = {0,0}, nC = {0,0}, oC = {0,0};
        float2 nD = {0,0}, oD = {0,0}, nE = {0,0}, oE = {0,0};
        if (ns > 0) { nA = *(const float2*)&Wx[(size_t)(cA & 255) * HID + j]; oA = *(const float2*)&Wx[(size_t)(cA >> 8) * HID + j]; }
        if (ns > 1) { nB = *(const float2*)&Wx[(size_t)(cB & 255) * HID + j]; oB = *(const float2*)&Wx[(size_t)(cB >> 8) * HID + j]; }
        if (ns > 2) { nC = *(const float2*)&Wx[(size_t)(cC & 255) * HID + j]; oC = *(const float2*)&Wx[(size_t)(cC >> 8) * HID + j]; }
        if (ns > 3) { nD = *(const float2*)&Wx[(size_t)(cD & 255) * HID + j]; oD = *(const float2*)&Wx[(size_t)(cD >> 8) * HID + j]; }
        if (ns > 4) { nE = *(const float2*)&Wx[(size_t)(cE & 255) * HID + j]; oE = *(const float2*)&Wx[(size_t)(cE >> 8) * HID + j]; }
        float dAx = nA.x - oA.x, dAy = nA.y - oA.y;
        float dBx = nB.x - oB.x, dBy = nB.y - oB.y;
        float dCx = nC.x - oC.x, dCy = nC.y - oC.y;
        float dDx = nD.x - oD.x, dDy = nD.y - oD.y;
        float dEx = nE.x - oE.x, dEy = nE.y - oE.y;
        float sw0 = 0.f, sw1 = 0.f;
        int sc = 0;
        for (int s = 0; s < nd; s++) {
            if ((chgMask >> s) & 1u) {           // uniform (scalar) branch
                float dx = (sc == 0) ? dAx : (sc == 1) ? dBx : (sc == 2) ? dCx : (sc == 3) ? dDx : dEx;
                float dy = (sc == 0) ? dAy : (sc == 1) ? dBy : (sc == 2) ? dCy : (sc == 3) ? dDy : dEy;
                sw0 += dx; sw1 += dy; sc++;
            }
            float4 u = u4s[tg][s];
            float h0 = hb.x + sw0 + u.x * w0.x + u.y * w1.x + u.z * wdl.x + u.w * wch.x;
            float h1 = hb.y + sw1 + u.x * w0.y + u.y * w1.y + u.z * wdl.y + u.w * wch.y;
            float s0 = h0 * __builtin_amdgcn_rcpf(1.f + __expf(-h0));
            float s1 = h1 * __builtin_amdgcn_rcpf(1.f + __expf(-h1));
            union { unsigned int u32; __bf16 h[2]; } pk;
            pk.h[0] = (__bf16)s0; pk.h[1] = (__bf16)s1;   // v_cvt_pk_bf16_f32 (RNE)
            *(unsigned int*)&S[(size_t)(tg * MAXS + s) * SROW + 2 * tl] = pk.u32;
        }
        __syncthreads();
        // Phase B: all 8 waves split K; each wave does k-chunks {wave, wave+8},
        // M=32 rows (both elements) per B-fragment load.
        const __bf16* Wb = (const __bf16*)W2T;
#pragma unroll
        for (int i = 0; i < 2; i++) {
            int kc = (wave + 8 * i) * 32 + q * 8;            // 0..511
            bf16x8 a0 = *(const bf16x8*)&S[(size_t)l15 * SROW + kc];
            bf16x8 a1 = *(const bf16x8*)&S[(size_t)(MAXS + l15) * SROW + kc];
            int kg = jt * TW + kc;
            bf16x8 b0  = *(const bf16x8*)&Wb[(size_t)l15 * HID + kg];
            bf16x8 b1v = *(const bf16x8*)&Wb[(size_t)(16 + l15) * HID + kg];
            bf16x8 b2v = *(const bf16x8*)&Wb[(size_t)(32 + l15) * HID + kg];
            acc[0][0] = __builtin_amdgcn_mfma_f32_16x16x32_bf16(a0, b0,  acc[0][0], 0, 0, 0);
            acc[0][1] = __builtin_amdgcn_mfma_f32_16x16x32_bf16(a0, b1v, acc[0][1], 0, 0, 0);
            acc[0][2] = __builtin_amdgcn_mfma_f32_16x16x32_bf16(a0, b2v, acc[0][2], 0, 0, 0);
            acc[1][0] = __builtin_amdgcn_mfma_f32_16x16x32_bf16(a1, b0,  acc[1][0], 0, 0, 0);
            acc[1][1] = __builtin_amdgcn_mfma_f32_16x16x32_bf16(a1, b1v, acc[1][1], 0, 0, 0);
            acc[1][2] = __builtin_amdgcn_mfma_f32_16x16x32_bf16(a1, b2v, acc[1][2], 0, 0, 0);
        }
    }
    __syncthreads();
    // 2-stage cross-wave reduction in dead S. Partial layout:
    // [wv(0..3)][mt(0..1)][row16][48] floats = 6144 floats (24,576 B).
    float* logitsP = (float*)S;
    float* logitsF = (float*)S + 6144;           // 1536 floats, ends at 30,720 B
    if (wave >= 4) {
        int wv = wave - 4;
#pragma unroll
        for (int mt = 0; mt < 2; mt++)
#pragma unroll
            for (int nt = 0; nt < 3; nt++)
#pragma unroll
                for (int r = 0; r < 4; r++)
                    logitsP[(size_t)(wv * 2 + mt) * 768 + (q * 4 + r) * 48 + nt * 16 + l15] = acc[mt][nt][r];
    }
    __syncthreads();
    if (wave < 4) {
        int wv = wave;
#pragma unroll
        for (int mt = 0; mt < 2; mt++)
#pragma unroll
            for (int nt = 0; nt < 3; nt++)
#pragma unroll
                for (int r = 0; r < 4; r++) {
                    size_t idx = (size_t)(wv * 2 + mt) * 768 + (q * 4 + r) * 48 + nt * 16 + l15;
                    logitsP[idx] += acc[mt][nt][r];
                }
    }
    __syncthreads();
    // final sum over 4 partials, 384 threads (192 per element)
    int tg2 = tid / 192, tl2 = tid - tg2 * 192;
    int tE = tl2 / 12, gE = tl2 - tE * 12;
    if (tid < 384) {
        const float4* P0 = (const float4*)(logitsP + (size_t)(0 * 2 + tg2) * 768);
        const float4* P1 = (const float4*)(logitsP + (size_t)(1 * 2 + tg2) * 768);
        const float4* P2 = (const float4*)(logitsP + (size_t)(2 * 2 + tg2) * 768);
        const float4* P3 = (const float4*)(logitsP + (size_t)(3 * 2 + tg2) * 768);
        float4 p0 = P0[tl2], p1 = P1[tl2], p2 = P2[tl2], p3 = P3[tl2];
        float4 bb = *(const float4*)&b2s[gE * 4];
        float4 r;
        r.x = p0.x + p1.x + p2.x + p3.x + bb.x;
        r.y = p0.y + p1.y + p2.y + p3.y + bb.y;
        r.z = p0.z + p1.z + p2.z + p3.z + bb.z;
        r.w = p0.w + p1.w + p2.w + p3.w + bb.w;
        ((float4*)(logitsF + tg2 * 768))[tl2] = r;
        float lm = (gE == 11) ? r.x : fmaxf(fmaxf(r.x, r.y), fmaxf(r.z, r.w));
        pmax[tg2][tE][gE] = lm;
    }
    __syncthreads();
    if (tid < 384 && gE == 0) {
        float m = pmax[tg2][tE][0];
        for (int i = 1; i < 12; i++) m = fmaxf(m, pmax[tg2][tE][i]);
        mxS[tg2][tE] = m;
    }
    __syncthreads();
    if (tid < 384) {
        float m = mxS[tg2][tE];
        float4 v = ((const float4*)(logitsF + tg2 * 768))[tl2];
        float s;
        if (gE == 11) s = __expf(v.x - m);
        else s = __expf(v.x - m) + __expf(v.y - m) + __expf(v.z - m) + __expf(v.w - m);
        psum[tg2][tE][gE] = s;
    }
    __syncthreads();
    if (tl < nd) {
        float ssum = 0.f;
        for (int i = 0; i < 12; i++) ssum += psum[tg][tl][i];
        float m = mxS[tg][tl];
        int dac = dacsS[tg][tl];
        float ld = logitsF[tg * 768 + tl * 48 + dac];
        float ce = -(ld - m - logf(ssum));
        ceArr[tg][tl] = ce * (float)multsS[tg][tl];
    }
    __syncthreads();
    if (tl == 0) {
        float s = 0.f;
        for (int t = 0; t < nd; t++) s += ceArr[tg][t];
        loss_out[bp * NB + tg] = s / (float)atS[tg];
    }
}

// ---------------------------------------------------------------------------
// Deterministic final reduction over 4096 per-b losses
// ---------------------------------------------------------------------------
__global__ void reduce_loss(const float* __restrict__ loss, float* __restrict__ out) {
    int tid = threadIdx.x;  // 256
    float s = 0.f;
    for (int i = tid; i < BATCH; i += 256) s += loss[i];
    for (int off = 32; off > 0; off >>= 1) s += __shfl_down(s, off, 64);
    __shared__ float wsum[4];
    if ((tid & 63) == 0) wsum[tid >> 6] = s;
    __syncthreads();
    if (tid == 0) out[0] = (wsum[0] + wsum[1] + wsum[2] + wsum[3]) * (1.0f / (float)BATCH);
}

// ---------------------------------------------------------------------------
extern "C" void kernel_launch(void* const* d_in, const int* in_sizes, int n_in,
                              void* d_out, int out_size, void* d_ws, size_t ws_size,
                              hipStream_t stream) {
    const float* fc_input = (const float*)d_in[0];
    const float* camera   = (const float*)d_in[1];
    const int*   fb       = (const int*)d_in[2];
    const int*   lr       = (const int*)d_in[3];
    const int*   jp       = (const int*)d_in[4];
    const int*   ss       = (const int*)d_in[5];
    const int*   at       = (const int*)d_in[6];
    const float* W1       = (const float*)d_in[7];
    const float* b1       = (const float*)d_in[8];
    const float* W2       = (const float*)d_in[9];
    const float* b2       = (const float*)d_in[10];
    float* out = (float*)d_out;

    char* ws = (char*)d_ws;
    unsigned short* Ab   = (unsigned short*)(ws);                       //  8,388,608 B
    unsigned short* Wt   = (unsigned short*)(ws + 8388608);             //  4,194,304 B
    float*          baseB= (float*)(ws + 12582912);                     // 33,554,432 B
    StepMeta*       meta = (StepMeta*)(ws + 46137344);                  //  2,097,152 B
    int2*           hdr  = (int2*)(ws + 48234496);                      //     32,768 B
    float*          lossB= (float*)(ws + 48267264);                     //     16,384 B
    unsigned short* W2T  = (unsigned short*)(ws + 48283648);            //    196,608 B

    prep_kernel<<<4096 + 2048 + 8 + 16, 256, 0, stream>>>(fc_input, Ab, W1, Wt, W2, W2T,
                                                          camera, fb, lr, jp, ss, at, meta, hdr);
    gemm_base<<<dim3(HID / 128, BATCH / 128), 256, 0, stream>>>(Ab, Wt, W1, b1, baseB);
    fused_mlp<<<BATCH / NB, 512, 0, stream>>>(baseB, W1, W2T, b2, meta, hdr, lossB);
    reduce_loss<<<1, 256, 0, stream>>>(lossB, out);
}

// Round 4
// 221.684 us; speedup vs baseline: 1.1820x; 1.0543x over previous
//
#include <hip/hip_runtime.h>

// Problem constants
#define BATCH 4096
#define NI 1024
#define HID 2048
#define TSTEPS 20
#define NA 45
#define TW 512    // fused j-tile width
#define SROW 520  // S row stride in bf16 elems (512 + 8 pad)
#define MAXS 16   // max distinct alive states per batch element (proven <= 15)
#define NB 2      // batch elements per fused_mlp block

typedef __bf16 bf16x8 __attribute__((ext_vector_type(8)));
typedef float floatx4 __attribute__((ext_vector_type(4)));

struct StepMeta {
    float ac0, ac1, delta, chosen;
    int chg;    // (oldCol<<8)|newCol applied entering this state, or -1
    int dac, mult, pad;
};

__device__ __forceinline__ unsigned short f2bf(float x) {
    union { float f; unsigned int u; } un; un.f = x;
    unsigned int r = un.u + 0x7FFFu + ((un.u >> 16) & 1u);
    return (unsigned short)(r >> 16);
}

// ---------------------------------------------------------------------------
// Per-batch-element 20-step state machine (exact fp32 replication),
// COMPRESSED: emits only distinct alive states; trailing fixed point gets a
// multiplicity; post-commit steps dropped. nd <= 15 < MAXS.
// Structural invariant exploited downstream: swap (chg>=0) states are the
// CONTIGUOUS PREFIX 1..ns (each pre-camera step resolves exactly one
// discrete mismatch, in priority order, before any delta/cam step).
// ---------------------------------------------------------------------------
__device__ void scan_one(int b, const float* __restrict__ camera,
                         const int* __restrict__ fb_in, const int* __restrict__ lr_in,
                         const int* __restrict__ jp_in, const int* __restrict__ ss_in,
                         const int* __restrict__ at_in, StepMeta* __restrict__ meta,
                         int2* __restrict__ hdr) {
    float cam0 = camera[2 * b], cam1 = camera[2 * b + 1];
    int afb = fb_in[b], alr = lr_in[b], ajp = jp_in[b], ass = ss_in[b], aat = at_in[b];
    float ac0 = 0.f, ac1 = 0.f, delta = 0.0625f;  // MIN_DELTA = 0.5/8
    int rfb = 0, rlr = 0, rjp = 0, rss = 0, rat = 0;
    bool chosen = false;
    int cam_steps = 0;
    int chgPending = -1;
    bool camzero = (fabsf(cam0) < 1e-5f) && (fabsf(cam1) < 1e-5f);
    int nd = 0, aliveTot = 0;
    float lac0 = 0.f, lac1 = 0.f, ldelta = 0.f, lchosen = 0.f;
    int ldac = -1000;
    for (int t = 0; t < TSTEPS; t++) {
        StepMeta m;
        m.ac0 = ac0; m.ac1 = ac1; m.delta = delta; m.chosen = chosen ? 1.f : 0.f;
        m.chg = chgPending; chgPending = -1;
        bool commit = (camzero || cam_steps >= 6) &&
                      rfb == afb && rlr == alr && rjp == ajp && rss == ass && rat == aat;
        int dac = 0; bool modified = commit;
        if (!modified && rfb != afb) { dac = (afb == 0 ? rfb - 1 + 6  : afb - 1 + 6 ); chgPending = ((2  + rfb) << 8) | (2  + afb); rfb = afb; modified = true; }
        if (!modified && rlr != alr) { dac = (alr == 0 ? rlr - 1 + 8  : alr - 1 + 8 ); chgPending = ((5  + rlr) << 8) | (5  + alr); rlr = alr; modified = true; }
        if (!modified && rjp != ajp) { dac = (ajp == 0 ? rjp - 1 + 10 : ajp - 1 + 10); chgPending = ((8  + rjp) << 8) | (8  + ajp); rjp = ajp; modified = true; }
        if (!modified && rss != ass) { dac = (ass == 0 ? rss - 1 + 11 : ass - 1 + 11); chgPending = ((10 + rss) << 8) | (10 + ass); rss = ass; modified = true; }
        if (!modified && rat != aat) { dac = (aat == 0 ? rat - 1 + 14 : aat - 1 + 14); chgPending = ((14 + rat) << 8) | (14 + aat); rat = aat; modified = true; }
        // NOTE: reference compares BOTH cam0 and cam1 against ac0 (replicated as-is)
        if (!modified && !chosen &&
            (fabsf(cam0 - ac0) > delta * 2.f || fabsf(cam1 - ac0) > delta * 2.f)) {
            dac = 5; delta = fminf(delta * 2.f, 0.5f); modified = true;
        }
        if (!modified) {
            bool incX = cam0 >= ac0, incY = cam1 >= ac1;
            dac = 1 + (incX ? 1 : 0) + (incY ? 2 : 0);
            ac0 += incX ? delta : -delta;
            ac1 += incY ? delta : -delta;
            delta *= 0.5f;
            chosen = true;
            cam_steps++;
        }
        m.dac = dac; m.mult = 1; m.pad = 0;
        // trailing fixed-point detection: identical state => identical forever
        if (nd > 0 && m.chg < 0 && !commit &&
            m.ac0 == lac0 && m.ac1 == lac1 && m.delta == ldelta &&
            m.chosen == lchosen && dac == ldac) {
            meta[b * MAXS + nd - 1].mult = 1 + (TSTEPS - t);
            aliveTot += (TSTEPS - t);
            break;
        }
        meta[b * MAXS + nd] = m;
        lac0 = m.ac0; lac1 = m.ac1; ldelta = m.delta; lchosen = m.chosen; ldac = dac;
        nd++; aliveTot++;
        if (commit) break;  // all remaining steps dead (alive=0 -> ce masked)
    }
    hdr[b] = make_int2(nd, aliveTot);
}

// ---------------------------------------------------------------------------
// Merged prep: convert_fc (blocks [0,4096)), transpose_w1 ([4096,6144)),
// convert_w2 ([6144,6152)), scan FSM ([6152,6168)) — one launch.
// ---------------------------------------------------------------------------
__global__ void prep_kernel(const float* __restrict__ fc, unsigned short* __restrict__ Ab,
                            const float* __restrict__ W1, unsigned short* __restrict__ Wt,
                            const float* __restrict__ W2, unsigned short* __restrict__ W2T,
                            const float* __restrict__ camera,
                            const int* __restrict__ fb_in, const int* __restrict__ lr_in,
                            const int* __restrict__ jp_in, const int* __restrict__ ss_in,
                            const int* __restrict__ at_in, StepMeta* __restrict__ meta,
                            int2* __restrict__ hdr) {
    __shared__ float tile[32][33];
    int bid = blockIdx.x, tid = threadIdx.x;
    if (bid < 4096) {
        int idx = bid * 256 + tid;  // covers BATCH*NI/4
        float4 v = ((const float4*)fc)[idx];
        ushort4 o;
        o.x = f2bf(v.x); o.y = f2bf(v.y); o.z = f2bf(v.z); o.w = f2bf(v.w);
        ((ushort4*)Ab)[idx] = o;
    } else if (bid < 6144) {
        int b2 = bid - 4096;
        int k0 = (b2 & 31) * 32, n0 = (b2 >> 5) * 32;
        int tx = tid & 31, ty = tid >> 5;  // (32, 8)
        for (int i = 0; i < 4; i++)
            tile[ty + 8 * i][tx] = W1[(size_t)(k0 + ty + 8 * i) * HID + n0 + tx];
        __syncthreads();
        for (int i = 0; i < 4; i++) {
            int n = ty + 8 * i;
            Wt[(size_t)(n0 + n) * NI + k0 + tx] = f2bf(tile[tx][n]);
        }
    } else if (bid < 6152) {
        int k = (bid - 6144) * 256 + tid;  // 0..2047
        for (int n = 0; n < 48; n++)
            W2T[(size_t)n * HID + k] = (n < NA) ? f2bf(W2[(size_t)k * NA + n]) : (unsigned short)0;
    } else {
        int b = (bid - 6152) * 256 + tid;  // 0..4095
        scan_one(b, camera, fb_in, lr_in, jp_in, ss_in, at_in, meta, hdr);
    }
}

// ---------------------------------------------------------------------------
// GEMM: base[4096][2048] = A @ W1[:1024] (bf16 MFMA, global_load_lds
// staging) + t=0-constant epilogue (b1 + initial one-hots + 0.0625*w_delta).
// ---------------------------------------------------------------------------
__global__ __launch_bounds__(256) void gemm_base(const unsigned short* __restrict__ Ab,
                                                 const unsigned short* __restrict__ Wt,
                                                 const float* __restrict__ W1,
                                                 const float* __restrict__ b1,
                                                 float* __restrict__ C) {
    __shared__ __align__(16) __bf16 At[128 * 32];
    __shared__ __align__(16) __bf16 Bt[128 * 32];
    int bn = blockIdx.x, bm = blockIdx.y;
    int m0 = bm * 128, n0 = bn * 128;
    int tid = threadIdx.x;
    int wave = tid >> 6, lane = tid & 63;
    int wr = wave >> 1, wc = wave & 1;
    int l15 = lane & 15, q = lane >> 4;
    floatx4 acc[4][4];
    for (int a = 0; a < 4; a++) for (int c = 0; c < 4; c++) acc[a][c] = (floatx4){0.f, 0.f, 0.f, 0.f};
    for (int k0 = 0; k0 < NI; k0 += 32) {
        __syncthreads();
#pragma unroll
        for (int i = 0; i < 2; i++) {
            int c = i * 256 + tid;
            int row = c >> 2, quarter = c & 3;
            const unsigned short* gA = &Ab[(size_t)(m0 + row) * NI + k0 + quarter * 8];
            const unsigned short* gB = &Wt[(size_t)(n0 + row) * NI + k0 + quarter * 8];
            __builtin_amdgcn_global_load_lds(
                (const __attribute__((address_space(1))) unsigned int*)gA,
                (__attribute__((address_space(3))) unsigned int*)&At[c * 8], 16, 0, 0);
            __builtin_amdgcn_global_load_lds(
                (const __attribute__((address_space(1))) unsigned int*)gB,
                (__attribute__((address_space(3))) unsigned int*)&Bt[c * 8], 16, 0, 0);
        }
        __syncthreads();
        bf16x8 af[4], bf[4];
        for (int mr = 0; mr < 4; mr++)
            af[mr] = *(const bf16x8*)&At[(wr * 64 + mr * 16 + l15) * 32 + q * 8];
        for (int nc = 0; nc < 4; nc++)
            bf[nc] = *(const bf16x8*)&Bt[(wc * 64 + nc * 16 + l15) * 32 + q * 8];
        for (int mr = 0; mr < 4; mr++)
            for (int nc = 0; nc < 4; nc++)
                acc[mr][nc] = __builtin_amdgcn_mfma_f32_16x16x32_bf16(af[mr], bf[nc], acc[mr][nc], 0, 0, 0);
    }
    for (int nc = 0; nc < 4; nc++) {
        int col = n0 + wc * 64 + nc * 16 + l15;
        const float* We = W1 + (size_t)NI * HID + col;
        float cv = b1[col] + We[2 * HID] + We[5 * HID] + We[8 * HID] + We[10 * HID]
                 + We[14 * HID] + 0.0625f * We[46 * HID];
        for (int mr = 0; mr < 4; mr++)
            for (int r = 0; r < 4; r++) {
                int row = m0 + wr * 64 + mr * 16 + q * 4 + r;
                C[(size_t)row * HID + col] = acc[mr][nc][r] + cv;
            }
    }
}

// ---------------------------------------------------------------------------
// Fused MLP + CE over COMPRESSED states, NB=2 batch elements per block.
// Phase A restructured for ILP: swap states (contiguous prefix 1..ns) are
// compile-time-unrolled with direct diff registers; remaining states run
// 2-per-iteration (4 independent silu chains/thread). Tree-form FMA.
// Phase B: M=32 tile, K split across 8 waves (R3 structure).
// ---------------------------------------------------------------------------
__global__ __launch_bounds__(512, 4) void fused_mlp(const float* __restrict__ base,
                                                 const float* __restrict__ W1,
                                                 const unsigned short* __restrict__ W2T,
                                                 const float* __restrict__ b2,
                                                 const StepMeta* __restrict__ meta,
                                                 const int2* __restrict__ hdr,
                                                 float* __restrict__ loss_out) {
    __shared__ __align__(16) __bf16 S[NB * MAXS * SROW];   // 33,280 B; pad rows zero
    __shared__ __align__(16) float4 u4s[NB][MAXS];         // (ac0, ac1, delta-d0, chosen)
    __shared__ int chgs[NB][MAXS], dacsS[NB][MAXS], multsS[NB][MAXS];
    __shared__ int swapL[NB][5], nsS[NB], ndS[NB], atS[NB];
    __shared__ float b2s[48];
    __shared__ float ceArr[NB][MAXS];
    __shared__ float pmax[NB][MAXS][12], psum[NB][MAXS][12], mxS[NB][MAXS];

    int bp = blockIdx.x, tid = threadIdx.x;
    int tg = tid >> 8, tl = tid & 255;           // group (=b within pair), local tid
    int wave = tid >> 6, lane = tid & 63, l15 = lane & 15, q = lane >> 4;

    if (tl == 0) {
        int2 hd = hdr[bp * NB + tg];
        ndS[tg] = hd.x; atS[tg] = hd.y;
    }
    if (tl < MAXS) {
        StepMeta m = meta[(size_t)(bp * NB + tg) * MAXS + tl];
        u4s[tg][tl] = make_float4(m.ac0, m.ac1, m.delta - 0.0625f, m.chosen);
        chgs[tg][tl] = m.chg; dacsS[tg][tl] = m.dac; multsS[tg][tl] = m.mult;
    }
    if (tid >= 64 && tid < 112) {
        int n = tid - 64;
        b2s[n] = (n < NA) ? b2[n] : 0.f;
    }
    __syncthreads();
    if (tl == 0) {
        int ns = 0, nd = ndS[tg];
        for (int s = 0; s < nd; s++)
            if (chgs[tg][s] >= 0) swapL[tg][ns++] = chgs[tg][s];
        nsS[tg] = ns;
        for (; ns < 5; ns++) swapL[tg][ns] = 0;
    }
    // zero the MFMA padding rows (row = 1040 B = 65 uint4)
    {
        int nd0 = ndS[0], nd1 = ndS[1];
        uint4 zz = make_uint4(0, 0, 0, 0);
        uint4* z0 = (uint4*)&S[(size_t)nd0 * SROW];
        int n0 = (MAXS - nd0) * 65;
        for (int i = tid; i < n0; i += 512) z0[i] = zz;
        uint4* z1 = (uint4*)&S[(size_t)(MAXS + nd1) * SROW];
        int n1 = (MAXS - nd1) * 65;
        for (int i = tid; i < n1; i += 512) z1[i] = zz;
    }
    __syncthreads();

    const float* Wx = W1 + (size_t)NI * HID;
    floatx4 acc[2][3];                           // [M-tile(=element)][n-tile]
    for (int a = 0; a < 2; a++) for (int c = 0; c < 3; c++) acc[a][c] = (floatx4){0.f, 0.f, 0.f, 0.f};

    int nd = __builtin_amdgcn_readfirstlane(ndS[tg]);
    int ns = __builtin_amdgcn_readfirstlane(nsS[tg]);
    int cA = __builtin_amdgcn_readfirstlane(swapL[tg][0]);
    int cB = __builtin_amdgcn_readfirstlane(swapL[tg][1]);
    int cC = __builtin_amdgcn_readfirstlane(swapL[tg][2]);
    int cD = __builtin_amdgcn_readfirstlane(swapL[tg][3]);
    int cE = __builtin_amdgcn_readfirstlane(swapL[tg][4]);

    for (int jt = 0; jt < 4; jt++) {
        if (jt) __syncthreads();                 // phase-B readers of prev tile done
        int j = jt * TW + 2 * tl;
        // hoisted loads: w-vectors, base, and ALL swap rows (load-only branches)
        float2 w0  = *(const float2*)&Wx[j];
        float2 w1  = *(const float2*)&Wx[HID + j];
        float2 wdl = *(const float2*)&Wx[46 * HID + j];
        float2 wch = *(const float2*)&Wx[47 * HID + j];
        float2 hb  = *(const float2*)&base[(size_t)(bp * NB + tg) * HID + j];
        float2 nA = {0,0}, oA = {0,0}, nB = {0,0}, oB = {0,0}, nC = {0,0}, oC = {0,0};
        float2 nD = {0,0}, oD = {0,0}, nE = {0,0}, oE = {0,0};
        if (ns > 0) { nA = *(const float2*)&Wx[(size_t)(cA & 255) * HID + j]; oA = *(const float2*)&Wx[(size_t)(cA >> 8) * HID + j]; }
        if (ns > 1) { nB = *(const float2*)&Wx[(size_t)(cB & 255) * HID + j]; oB = *(const float2*)&Wx[(size_t)(cB >> 8) * HID + j]; }
        if (ns > 2) { nC = *(const float2*)&Wx[(size_t)(cC & 255) * HID + j]; oC = *(const float2*)&Wx[(size_t)(cC >> 8) * HID + j]; }
        if (ns > 3) { nD = *(const float2*)&Wx[(size_t)(cD & 255) * HID + j]; oD = *(const float2*)&Wx[(size_t)(cD >> 8) * HID + j]; }
        if (ns > 4) { nE = *(const float2*)&Wx[(size_t)(cE & 255) * HID + j]; oE = *(const float2*)&Wx[(size_t)(cE >> 8) * HID + j]; }

        // one silu state: h = ((bx + u.x*w0) + (u.y*w1 + u.z*wdl)) + u.w*wch
        auto compute1 = [&](int s, float bx, float by) {
            float4 u = u4s[tg][s];
            float t0 = fmaf(u.x, w0.x, bx);
            float m0 = u.y * w1.x;  m0 = fmaf(u.z, wdl.x, m0);
            t0 = fmaf(u.w, wch.x, t0);
            float h0 = t0 + m0;
            float t1 = fmaf(u.x, w0.y, by);
            float m1 = u.y * w1.y;  m1 = fmaf(u.z, wdl.y, m1);
            t1 = fmaf(u.w, wch.y, t1);
            float h1 = t1 + m1;
            float s0 = h0 * __builtin_amdgcn_rcpf(1.f + __expf(-h0));
            float s1 = h1 * __builtin_amdgcn_rcpf(1.f + __expf(-h1));
            union { unsigned int u32; __bf16 h[2]; } pk;
            pk.h[0] = (__bf16)s0; pk.h[1] = (__bf16)s1;   // v_cvt_pk_bf16_f32 (RNE)
            *(unsigned int*)&S[(size_t)(tg * MAXS + s) * SROW + 2 * tl] = pk.u32;
        };

        // swap-prefix states (contiguous, compile-time unrolled; ns uniform)
        float swx = 0.f, swy = 0.f;
        compute1(0, hb.x, hb.y);
        if (ns > 0) { swx += nA.x - oA.x; swy += nA.y - oA.y; compute1(1, hb.x + swx, hb.y + swy); }
        if (ns > 1) { swx += nB.x - oB.x; swy += nB.y - oB.y; compute1(2, hb.x + swx, hb.y + swy); }
        if (ns > 2) { swx += nC.x - oC.x; swy += nC.y - oC.y; compute1(3, hb.x + swx, hb.y + swy); }
        if (ns > 3) { swx += nD.x - oD.x; swy += nD.y - oD.y; compute1(4, hb.x + swx, hb.y + swy); }
        if (ns > 4) { swx += nE.x - oE.x; swy += nE.y - oE.y; compute1(5, hb.x + swx, hb.y + swy); }
        // tail states (no swaps): 2 per iteration -> 4 independent silu chains
        float bx = hb.x + swx, by = hb.y + swy;
        int s = ns + 1;
        for (; s + 1 < nd; s += 2) {
            compute1(s, bx, by);
            compute1(s + 1, bx, by);
        }
        if (s < nd) compute1(s, bx, by);

        __syncthreads();
        // Phase B: all 8 waves split K; each wave does k-chunks {wave, wave+8},
        // M=32 rows (both elements) per B-fragment load.
        const __bf16* Wb = (const __bf16*)W2T;
#pragma unroll
        for (int i = 0; i < 2; i++) {
            int kc = (wave + 8 * i) * 32 + q * 8;            // 0..511
            bf16x8 a0 = *(const bf16x8*)&S[(size_t)l15 * SROW + kc];
            bf16x8 a1 = *(const bf16x8*)&S[(size_t)(MAXS + l15) * SROW + kc];
            int kg = jt * TW + kc;
            bf16x8 b0  = *(const bf16x8*)&Wb[(size_t)l15 * HID + kg];
            bf16x8 b1v = *(const bf16x8*)&Wb[(size_t)(16 + l15) * HID + kg];
            bf16x8 b2v = *(const bf16x8*)&Wb[(size_t)(32 + l15) * HID + kg];
            acc[0][0] = __builtin_amdgcn_mfma_f32_16x16x32_bf16(a0, b0,  acc[0][0], 0, 0, 0);
            acc[0][1] = __builtin_amdgcn_mfma_f32_16x16x32_bf16(a0, b1v, acc[0][1], 0, 0, 0);
            acc[0][2] = __builtin_amdgcn_mfma_f32_16x16x32_bf16(a0, b2v, acc[0][2], 0, 0, 0);
            acc[1][0] = __builtin_amdgcn_mfma_f32_16x16x32_bf16(a1, b0,  acc[1][0], 0, 0, 0);
            acc[1][1] = __builtin_amdgcn_mfma_f32_16x16x32_bf16(a1, b1v, acc[1][1], 0, 0, 0);
            acc[1][2] = __builtin_amdgcn_mfma_f32_16x16x32_bf16(a1, b2v, acc[1][2], 0, 0, 0);
        }
    }
    __syncthreads();
    // 2-stage cross-wave reduction in dead S. Partial layout:
    // [wv(0..3)][mt(0..1)][row16][48] floats = 6144 floats (24,576 B).
    float* logitsP = (float*)S;
    float* logitsF = (float*)S + 6144;           // 1536 floats, ends at 30,720 B
    if (wave >= 4) {
        int wv = wave - 4;
#pragma unroll
        for (int mt = 0; mt < 2; mt++)
#pragma unroll
            for (int nt = 0; nt < 3; nt++)
#pragma unroll
                for (int r = 0; r < 4; r++)
                    logitsP[(size_t)(wv * 2 + mt) * 768 + (q * 4 + r) * 48 + nt * 16 + l15] = acc[mt][nt][r];
    }
    __syncthreads();
    if (wave < 4) {
        int wv = wave;
#pragma unroll
        for (int mt = 0; mt < 2; mt++)
#pragma unroll
            for (int nt = 0; nt < 3; nt++)
#pragma unroll
                for (int r = 0; r < 4; r++) {
                    size_t idx = (size_t)(wv * 2 + mt) * 768 + (q * 4 + r) * 48 + nt * 16 + l15;
                    logitsP[idx] += acc[mt][nt][r];
                }
    }
    __syncthreads();
    // final sum over 4 partials, 384 threads (192 per element)
    int tg2 = tid / 192, tl2 = tid - tg2 * 192;
    int tE = tl2 / 12, gE = tl2 - tE * 12;
    if (tid < 384) {
        const float4* P0 = (const float4*)(logitsP + (size_t)(0 * 2 + tg2) * 768);
        const float4* P1 = (const float4*)(logitsP + (size_t)(1 * 2 + tg2) * 768);
        const float4* P2 = (const float4*)(logitsP + (size_t)(2 * 2 + tg2) * 768);
        const float4* P3 = (const float4*)(logitsP + (size_t)(3 * 2 + tg2) * 768);
        float4 p0 = P0[tl2], p1 = P1[tl2], p2 = P2[tl2], p3 = P3[tl2];
        float4 bb = *(const float4*)&b2s[gE * 4];
        float4 r;
        r.x = p0.x + p1.x + p2.x + p3.x + bb.x;
        r.y = p0.y + p1.y + p2.y + p3.y + bb.y;
        r.z = p0.z + p1.z + p2.z + p3.z + bb.z;
        r.w = p0.w + p1.w + p2.w + p3.w + bb.w;
        ((float4*)(logitsF + tg2 * 768))[tl2] = r;
        float lm = (gE == 11) ? r.x : fmaxf(fmaxf(r.x, r.y), fmaxf(r.z, r.w));
        pmax[tg2][tE][gE] = lm;
    }
    __syncthreads();
    if (tid < 384 && gE == 0) {
        float m = pmax[tg2][tE][0];
        for (int i = 1; i < 12; i++) m = fmaxf(m, pmax[tg2][tE][i]);
        mxS[tg2][tE] = m;
    }
    __syncthreads();
    if (tid < 384) {
        float m = mxS[tg2][tE];
        float4 v = ((const float4*)(logitsF + tg2 * 768))[tl2];
        float s;
        if (gE == 11) s = __expf(v.x - m);
        else s = __expf(v.x - m) + __expf(v.y - m) + __expf(v.z - m) + __expf(v.w - m);
        psum[tg2][tE][gE] = s;
    }
    __syncthreads();
    if (tl < nd) {
        float ssum = 0.f;
        for (int i = 0; i < 12; i++) ssum += psum[tg][tl][i];
        float m = mxS[tg][tl];
        int dac = dacsS[tg][tl];
        float ld = logitsF[tg * 768 + tl * 48 + dac];
        float ce = -(ld - m - logf(ssum));
        ceArr[tg][tl] = ce * (float)multsS[tg][tl];
    }
    __syncthreads();
    if (tl == 0) {
        float s = 0.f;
        for (int t = 0; t < nd; t++) s += ceArr[tg][t];
        loss_out[bp * NB + tg] = s / (float)atS[tg];
    }
}

// ---------------------------------------------------------------------------
// Deterministic final reduction over 4096 per-b losses
// ---------------------------------------------------------------------------
__global__ void reduce_loss(const float* __restrict__ loss, float* __restrict__ out) {
    int tid = threadIdx.x;  // 256
    float s = 0.f;
    for (int i = tid; i < BATCH; i += 256) s += loss[i];
    for (int off = 32; off > 0; off >>= 1) s += __shfl_down(s, off, 64);
    __shared__ float wsum[4];
    if ((tid & 63) == 0) wsum[tid >> 6] = s;
    __syncthreads();
    if (tid == 0) out[0] = (wsum[0] + wsum[1] + wsum[2] + wsum[3]) * (1.0f / (float)BATCH);
}

// ---------------------------------------------------------------------------
extern "C" void kernel_launch(void* const* d_in, const int* in_sizes, int n_in,
                              void* d_out, int out_size, void* d_ws, size_t ws_size,
                              hipStream_t stream) {
    const float* fc_input = (const float*)d_in[0];
    const float* camera   = (const float*)d_in[1];
    const int*   fb       = (const int*)d_in[2];
    const int*   lr       = (const int*)d_in[3];
    const int*   jp       = (const int*)d_in[4];
    const int*   ss       = (const int*)d_in[5];
    const int*   at       = (const int*)d_in[6];
    const float* W1       = (const float*)d_in[7];
    const float* b1       = (const float*)d_in[8];
    const float* W2       = (const float*)d_in[9];
    const float* b2       = (const float*)d_in[10];
    float* out = (float*)d_out;

    char* ws = (char*)d_ws;
    unsigned short* Ab   = (unsigned short*)(ws);                       //  8,388,608 B
    unsigned short* Wt   = (unsigned short*)(ws + 8388608);             //  4,194,304 B
    float*          baseB= (float*)(ws + 12582912);                     // 33,554,432 B
    StepMeta*       meta = (StepMeta*)(ws + 46137344);                  //  2,097,152 B
    int2*           hdr  = (int2*)(ws + 48234496);                      //     32,768 B
    float*          lossB= (float*)(ws + 48267264);                     //     16,384 B
    unsigned short* W2T  = (unsigned short*)(ws + 48283648);            //    196,608 B

    prep_kernel<<<4096 + 2048 + 8 + 16, 256, 0, stream>>>(fc_input, Ab, W1, Wt, W2, W2T,
                                                          camera, fb, lr, jp, ss, at, meta, hdr);
    gemm_base<<<dim3(HID / 128, BATCH / 128), 256, 0, stream>>>(Ab, Wt, W1, b1, baseB);
    fused_mlp<<<BATCH / NB, 512, 0, stream>>>(baseB, W1, W2T, b2, meta, hdr, lossB);
    reduce_loss<<<1, 256, 0, stream>>>(lossB, out);
}